// Round 7
// baseline (3710.510 us; speedup 1.0000x reference)
//
#include <hip/hip_runtime.h>
#include <hip/hip_bf16.h>

typedef unsigned short u16;
typedef unsigned int u32;
typedef __attribute__((ext_vector_type(8))) __bf16 bf16x8;
typedef __attribute__((ext_vector_type(4))) float f32x4;
typedef __attribute__((ext_vector_type(4))) u16 u16x4;
typedef __attribute__((ext_vector_type(8))) u16 u16x8;

#define SCUR 4096
#define SMEM 16384
#define DM   256
#define DFFN 2048
#define NL   4

__device__ __forceinline__ u16 f2b(float f){
  u32 i; __builtin_memcpy(&i, &f, 4);
  u32 r = (i + 0x7fffu + ((i >> 16) & 1u)) >> 16;
  return (u16)r;
}
__device__ __forceinline__ float b2f(u16 v){
  u32 i = ((u32)v) << 16; float f; __builtin_memcpy(&f, &i, 4); return f;
}

__device__ __forceinline__ f32x4 mfma16(bf16x8 a, bf16x8 b, f32x4 c){
  return __builtin_amdgcn_mfma_f32_16x16x32_bf16(a, b, c, 0, 0, 0);
}

// ---------------- elementwise prep ----------------

__global__ void axpy_k(const float* __restrict__ a, const float* __restrict__ b,
                       float s, float* __restrict__ o, int n4){
  int i = blockIdx.x * blockDim.x + threadIdx.x;
  int st = gridDim.x * blockDim.x;
  for (; i < n4; i += st){
    float4 x = ((const float4*)a)[i];
    float4 y = ((const float4*)b)[i];
    float4 r; r.x = x.x + s*y.x; r.y = x.y + s*y.y; r.z = x.z + s*y.z; r.w = x.w + s*y.w;
    ((float4*)o)[i] = r;
  }
}

__global__ void cvt_bf16_k(const float* __restrict__ a, const float* __restrict__ b,
                           u16* __restrict__ o, int n4, float s){
  int i = blockIdx.x * blockDim.x + threadIdx.x;
  int st = gridDim.x * blockDim.x;
  const bool hb = (b != nullptr);
  for (; i < n4; i += st){
    float4 x = ((const float4*)a)[i];
    if (hb){
      float4 y = ((const float4*)b)[i];
      x.x += s*y.x; x.y += s*y.y; x.z += s*y.z; x.w += s*y.w;
    }
    u16x4 r = { f2b(x.x), f2b(x.y), f2b(x.z), f2b(x.w) };
    ((u16x4*)o)[i] = r;
  }
}

// ---------------- layernorm ----------------
template<int OUTF32>
__global__ __launch_bounds__(256) void ln_k(const float* __restrict__ X,
    const float* __restrict__ g, const float* __restrict__ b,
    void* __restrict__ out, int rows){
  int row = blockIdx.x * 4 + (threadIdx.x >> 6);
  int lane = threadIdx.x & 63;
  if (row >= rows) return;
  const float4 v = *(const float4*)(X + (size_t)row*DM + lane*4);
  float s = v.x + v.y + v.z + v.w;
  for (int off = 1; off < 64; off <<= 1) s += __shfl_xor(s, off, 64);
  float mu = s * (1.f/256.f);
  float dx = v.x-mu, dy = v.y-mu, dz = v.z-mu, dw = v.w-mu;
  float q = dx*dx + dy*dy + dz*dz + dw*dw;
  for (int off = 1; off < 64; off <<= 1) q += __shfl_xor(q, off, 64);
  float rstd = rsqrtf(q * (1.f/256.f) + 1e-5f);
  const float4 gw = *(const float4*)(g + lane*4);
  const float4 gb = *(const float4*)(b + lane*4);
  float y0 = dx*rstd*gw.x + gb.x;
  float y1 = dy*rstd*gw.y + gb.y;
  float y2 = dz*rstd*gw.z + gb.z;
  float y3 = dw*rstd*gw.w + gb.w;
  if (OUTF32){
    float4 o; o.x=y0; o.y=y1; o.z=y2; o.w=y3;
    *(float4*)((float*)out + (size_t)row*DM + lane*4) = o;
  } else {
    u16x4 o = { f2b(y0), f2b(y1), f2b(y2), f2b(y3) };
    *(u16x4*)((u16*)out + (size_t)row*DM + lane*4) = o;
  }
}

// ---------------- GEMM: C[M][N] = A[M][K] * W[N][K]^T + bias ----------------
template<int EPI>
__global__ __launch_bounds__(256) void gemm_bt(
    const u16* __restrict__ A, const u16* __restrict__ W,
    const float* __restrict__ bias, void* __restrict__ out,
    int M, int N, int K){
  __shared__ u16 a_sm[64*40];
  __shared__ u16 b_sm[64*40];
  const int tid = threadIdx.x;
  const int lane = tid & 63;
  const int w = tid >> 6;
  const int l16 = lane & 15, lg = lane >> 4;
  const int m0 = blockIdx.y * 64;
  const int n0 = blockIdx.x * 64;
  const int wr = (w >> 1) * 32, wc = (w & 1) * 32;
  f32x4 acc[2][2] = {};
  const int srow = tid >> 2, sch = tid & 3;
  const u16* Ag = A + (size_t)(m0 + srow) * K + sch * 8;
  const u16* Wg = W + (size_t)(n0 + srow) * K + sch * 8;
  for (int k0 = 0; k0 < K; k0 += 32){
    u16x8 av = *(const u16x8*)(Ag + k0);
    u16x8 wv = *(const u16x8*)(Wg + k0);
    __syncthreads();
    *(u16x8*)(a_sm + srow*40 + sch*8) = av;
    *(u16x8*)(b_sm + srow*40 + sch*8) = wv;
    __syncthreads();
    bf16x8 af0 = *(const bf16x8*)(a_sm + (wr      + l16)*40 + lg*8);
    bf16x8 af1 = *(const bf16x8*)(a_sm + (wr + 16 + l16)*40 + lg*8);
    bf16x8 bf0 = *(const bf16x8*)(b_sm + (wc      + l16)*40 + lg*8);
    bf16x8 bf1 = *(const bf16x8*)(b_sm + (wc + 16 + l16)*40 + lg*8);
    acc[0][0] = mfma16(af0, bf0, acc[0][0]);
    acc[0][1] = mfma16(af0, bf1, acc[0][1]);
    acc[1][0] = mfma16(af1, bf0, acc[1][0]);
    acc[1][1] = mfma16(af1, bf1, acc[1][1]);
  }
  for (int mi = 0; mi < 2; mi++)
    for (int ni = 0; ni < 2; ni++)
      for (int r = 0; r < 4; r++){
        int m = m0 + wr + mi*16 + lg*4 + r;
        int n = n0 + wc + ni*16 + l16;
        float v = acc[mi][ni][r] + bias[n];
        if (EPI == 0)      ((u16*)out)[(size_t)m*N + n] = f2b(v);
        else if (EPI == 1) ((u16*)out)[(size_t)m*N + n] = f2b(v > 0.f ? v : 0.f);
        else               ((float*)out)[(size_t)m*N + n] += v;
      }
}

// ---------------- flash attention (single head, hd=256) ----------------
// 256 threads = 4 waves, QBLK=64 (wave w owns q-rows qrow0..+16, lane's q = l16).
// SWAPPED QK^T: sa = mfma(K, Q) -> lane holds S[16 keys][its q] -> in-register
// softmax (2 shfls). K,Q read direct from XCD-pinned L2. V staged in-tile
// (loads hidden under softmax). Defer-max rescale (THR=8). bf16 O partials.
// grid = (Sq/64) << shift; split = bid & (nsplit-1) -> XCD-pinned KV chunk.
__global__ __launch_bounds__(256, 4) void flash_k(
    const u16* __restrict__ Q, int qs,
    const u16* __restrict__ K, int kss,
    const u16* __restrict__ V, int vss,
    u16* __restrict__ Op, float* __restrict__ mp, float* __restrict__ lp,
    int Sq, int kvChunk, int shift){
  __shared__ u16 vtsm[256*64];  // V^T tile: byte d*128 + ((kc^s(d))*16) + half*8
  __shared__ u16 psm[4*1024];   // per-wave P tile 16x64, chunk swizzle ch^(q&7)
  const int bid = blockIdx.x;
  const int split = bid & ((1 << shift) - 1);
  const int qtile = bid >> shift;
  const int tid = threadIdx.x, lane = tid & 63, w = tid >> 6;
  const int l16 = lane & 15, lg = lane >> 4;
  const int qrow0 = qtile * 64 + w * 16;
  const int kv0 = split * kvChunk;
  const int nt = kvChunk >> 6;
  const u16* Kg = K + (size_t)kv0 * kss;
  const u16* Vg = V + (size_t)kv0 * vss;
  const u16* qp = Q + (size_t)(qrow0 + l16) * qs + lg * 8;  // B-operand (col=q)

  f32x4 oa[16] = {};
  float mst = -1e30f, lst = 0.f;

  for (int t = 0; t < nt; t++){
    // barrier A: all waves done PV-reading vtsm(t-1)
    asm volatile("s_waitcnt lgkmcnt(0)" ::: "memory");
    __builtin_amdgcn_s_barrier();

    // ---- S^T = (K Q^T)/16 : both operands straight from L2 ----
    const u16* Kt = Kg + (size_t)t * 64 * kss;
    f32x4 sa[4] = {};
    #pragma unroll
    for (int ks = 0; ks < 8; ks++){
      bf16x8 qf = *(const bf16x8*)(qp + ks*32);
      #pragma unroll
      for (int c = 0; c < 4; c++){
        bf16x8 kf = *(const bf16x8*)(Kt + (size_t)(c*16 + l16)*kss + ks*32 + lg*8);
        sa[c] = mfma16(kf, qf, sa[c]);   // swapped: row=key, col=q
      }
    }
    #pragma unroll
    for (int c = 0; c < 4; c++)
      #pragma unroll
      for (int r = 0; r < 4; r++) sa[c][r] *= 0.0625f;

    // ---- issue V loads (latency hides under softmax) ----
    u16x8 vr[8];
    const u16* Vt = Vg + (size_t)t * 64 * vss;
    #pragma unroll
    for (int j = 0; j < 2; j++){
      int task = tid + j*256; int kg = task & 15; int dg = task >> 4;
      #pragma unroll
      for (int i = 0; i < 4; i++)
        vr[j*4+i] = *(const u16x8*)(Vt + (size_t)(kg*4 + i)*vss + dg*8);
    }
    __builtin_amdgcn_sched_barrier(0);

    // ---- softmax: in-register over 16 keys + 2 cross-group shfls ----
    float mx = sa[0][0];
    #pragma unroll
    for (int c = 0; c < 4; c++)
      #pragma unroll
      for (int r = 0; r < 4; r++) mx = fmaxf(mx, sa[c][r]);
    mx = fmaxf(mx, __shfl_xor(mx, 16, 64));
    mx = fmaxf(mx, __shfl_xor(mx, 32, 64));

    if (!__all(mx <= mst + 8.f)){
      float mn = fmaxf(mst, mx);
      float al = __expf(mst - mn);
      mst = mn;
      lst *= al;
      #pragma unroll
      for (int r = 0; r < 4; r++){
        float af = __shfl(al, 4*lg + r, 64);
        #pragma unroll
        for (int dc = 0; dc < 16; dc++) oa[dc][r] *= af;
      }
    }
    float rs = 0.f;
    #pragma unroll
    for (int c = 0; c < 4; c++)
      #pragma unroll
      for (int r = 0; r < 4; r++){
        float pv = __expf(sa[c][r] - mst);
        sa[c][r] = pv;
        rs += pv;
      }
    rs += __shfl_xor(rs, 16, 64);
    rs += __shfl_xor(rs, 32, 64);
    lst += rs;

    // ---- V^T writes from regs (b64, ~4-way max) ----
    asm volatile("s_waitcnt vmcnt(0)" ::: "memory");  // V landed (kf long done)
    #pragma unroll
    for (int j = 0; j < 2; j++){
      int task = tid + j*256; int kg = task & 15; int dg = task >> 4;
      #pragma unroll
      for (int e = 0; e < 8; e++){
        int d = dg*8 + e;
        int s2 = (d + (d >> 3)) & 7;
        int kc = kg >> 1;
        u16x4 wv = { (u16)vr[j*4+0][e], (u16)vr[j*4+1][e],
                     (u16)vr[j*4+2][e], (u16)vr[j*4+3][e] };
        *(u16x4*)((char*)vtsm + d*128 + ((kc ^ s2) << 4) + (kg & 1)*8) = wv;
      }
    }

    // ---- P (bf16) -> per-wave psm: 4 x ds_write_b64 ----
    {
      u16* pw = psm + w*1024;
      #pragma unroll
      for (int c = 0; c < 4; c++){
        int kc = 2*c + (lg >> 1);
        int x = kc ^ (l16 & 7);
        u16x4 pv4 = { f2b(sa[c][0]), f2b(sa[c][1]), f2b(sa[c][2]), f2b(sa[c][3]) };
        *(u16x4*)((char*)pw + l16*128 + (x << 4) + (lg & 1)*8) = pv4;
      }
    }

    // barrier B: vtsm(t) ready for all waves
    asm volatile("s_waitcnt lgkmcnt(0)" ::: "memory");
    __builtin_amdgcn_s_barrier();

    // ---- O += P V ----
    bf16x8 pf[2];
    {
      const u16* pb = psm + w*1024;
      #pragma unroll
      for (int ks2 = 0; ks2 < 2; ks2++){
        int ch = ks2*4 + lg;
        int sc2 = ch ^ (l16 & 7);
        pf[ks2] = *(const bf16x8*)(pb + l16*64 + sc2*8);
      }
    }
    __builtin_amdgcn_s_setprio(1);
    #pragma unroll
    for (int dc = 0; dc < 16; dc++){
      int d = dc*16 + l16;
      int s2 = (d + (d >> 3)) & 7;
      #pragma unroll
      for (int ks2 = 0; ks2 < 2; ks2++){
        int ch = ks2*4 + lg;
        int sc2 = ch ^ s2;
        bf16x8 vf = *(const bf16x8*)(vtsm + d*64 + sc2*8);
        oa[dc] = mfma16(pf[ks2], vf, oa[dc]);
      }
    }
    __builtin_amdgcn_s_setprio(0);
  }

  // partials out (bf16): oa row = q = 4*lg + r
  u16* Obase = Op + (size_t)split * Sq * DM;
  #pragma unroll
  for (int dc = 0; dc < 16; dc++)
    #pragma unroll
    for (int r = 0; r < 4; r++){
      int q = qrow0 + lg*4 + r;
      int d = dc*16 + l16;
      Obase[(size_t)q*DM + d] = f2b(oa[dc][r]);
    }
  if (lane < 16){
    mp[(size_t)split*Sq + qrow0 + lane] = mst;
    lp[(size_t)split*Sq + qrow0 + lane] = lst;
  }
}

// combine KV-split partials (bf16) -> bf16 O
__global__ __launch_bounds__(256) void combine_k(const u16* __restrict__ Op,
    const float* __restrict__ mp, const float* __restrict__ lp,
    u16* __restrict__ Ob, int Sq, int nsplit){
  int q = blockIdx.x;
  int d = threadIdx.x;
  float mM = -1e30f;
  for (int i = 0; i < nsplit; i++) mM = fmaxf(mM, mp[(size_t)i*Sq + q]);
  float Ls = 0.f, acc = 0.f;
  for (int i = 0; i < nsplit; i++){
    float wgt = __expf(mp[(size_t)i*Sq + q] - mM);
    Ls  += lp[(size_t)i*Sq + q] * wgt;
    acc += wgt * b2f(Op[((size_t)i*Sq + q)*DM + d]);
  }
  Ob[(size_t)q*DM + d] = f2b(acc / Ls);
}

// ---------------- launch ----------------
extern "C" void kernel_launch(void* const* d_in, const int* in_sizes, int n_in,
                              void* d_out, int out_size, void* d_ws, size_t ws_size,
                              hipStream_t stream){
  (void)in_sizes; (void)n_in; (void)out_size;
  const float* curr       = (const float*)d_in[0];
  const float* memory     = (const float*)d_in[1];
  const float* curr_pos   = (const float*)d_in[2];
  const float* memory_pos = (const float*)d_in[3];
  const float* sa_w_qkv   = (const float*)d_in[4];
  const float* sa_b_qkv   = (const float*)d_in[5];
  const float* sa_w_o     = (const float*)d_in[6];
  const float* sa_b_o     = (const float*)d_in[7];
  const float* ca_w_qkv   = (const float*)d_in[8];
  const float* ca_b_qkv   = (const float*)d_in[9];
  const float* ca_w_o     = (const float*)d_in[10];
  const float* ca_b_o     = (const float*)d_in[11];
  const float* ln1_w = (const float*)d_in[12];
  const float* ln1_b = (const float*)d_in[13];
  const float* ln2_w = (const float*)d_in[14];
  const float* ln2_b = (const float*)d_in[15];
  const float* ln3_w = (const float*)d_in[16];
  const float* ln3_b = (const float*)d_in[17];
  const float* mlp_w1 = (const float*)d_in[18];
  const float* mlp_b1 = (const float*)d_in[19];
  const float* mlp_w2 = (const float*)d_in[20];
  const float* mlp_b2 = (const float*)d_in[21];
  const float* norm_w = (const float*)d_in[22];
  const float* norm_b = (const float*)d_in[23];

  const int nsplit = (ws_size >= (size_t)94*1024*1024) ? 16 : 8;
  const int shift  = (nsplit == 16) ? 4 : 3;

  char* wsp = (char*)d_ws;
  auto alloc = [&](size_t bytes)->void*{
    void* r = (void*)wsp; wsp += (bytes + 255) & ~(size_t)255; return r;
  };
  float* x     = (float*)alloc((size_t)SCUR*DM*4);
  u16*   t2b   = (u16*)  alloc((size_t)SCUR*DM*2);
  u16*   qkvb  = (u16*)  alloc((size_t)SCUR*3*DM*2);   // fused self QKV [S][768]; cross Q aliases
  u16*   Kb    = (u16*)  alloc((size_t)SMEM*DM*2);
  u16*   Vb    = (u16*)  alloc((size_t)SMEM*DM*2);
  u16*   memkb = (u16*)  alloc((size_t)SMEM*DM*2);
  u16*   memb  = (u16*)  alloc((size_t)SMEM*DM*2);
  // union: MLP hidden (16MB) aliases bf16 attention partials (nsplit*2MB)
  size_t uni_bytes = (size_t)SCUR*DFFN*2;
  size_t op_bytes  = (size_t)nsplit*SCUR*DM*2;
  char*  uni   = (char*) alloc(uni_bytes > op_bytes ? uni_bytes : op_bytes);
  u16*   Hb    = (u16*)uni;
  u16*   Opart = (u16*)uni;
  float* mpart = (float*)alloc((size_t)16*SCUR*4);
  float* lpart = (float*)alloc((size_t)16*SCUR*4);
  u16* wb_sa_qkv = (u16*)alloc((size_t)NL*3*DM*DM*2);
  u16* wb_sa_o   = (u16*)alloc((size_t)NL*DM*DM*2);
  u16* wb_ca_qkv = (u16*)alloc((size_t)NL*3*DM*DM*2);
  u16* wb_ca_o   = (u16*)alloc((size_t)NL*DM*DM*2);
  u16* wb_m1     = (u16*)alloc((size_t)NL*DFFN*DM*2);
  u16* wb_m2     = (u16*)alloc((size_t)NL*DM*DFFN*2);

  u16* Ob = t2b;      // alias: t2b dead after QKV gemm, before combine writes
  u16* Qb = qkvb;     // alias: qkvb free during cross-attention

  const float* nullf = nullptr;

  axpy_k<<<dim3(512), dim3(256), 0, stream>>>(curr, curr_pos, 0.1f, x, SCUR*DM/4);
  cvt_bf16_k<<<dim3(1024), dim3(256), 0, stream>>>(memory, memory_pos, memkb, SMEM*DM/4, 1.0f);
  cvt_bf16_k<<<dim3(1024), dim3(256), 0, stream>>>(memory, nullf, memb, SMEM*DM/4, 0.f);
  cvt_bf16_k<<<dim3(512), dim3(256), 0, stream>>>(sa_w_qkv, nullf, wb_sa_qkv, NL*3*DM*DM/4, 0.f);
  cvt_bf16_k<<<dim3(256), dim3(256), 0, stream>>>(sa_w_o,   nullf, wb_sa_o,   NL*DM*DM/4,   0.f);
  cvt_bf16_k<<<dim3(512), dim3(256), 0, stream>>>(ca_w_qkv, nullf, wb_ca_qkv, NL*3*DM*DM/4, 0.f);
  cvt_bf16_k<<<dim3(256), dim3(256), 0, stream>>>(ca_w_o,   nullf, wb_ca_o,   NL*DM*DM/4,   0.f);
  cvt_bf16_k<<<dim3(1024), dim3(256), 0, stream>>>(mlp_w1,  nullf, wb_m1,     NL*DFFN*DM/4, 0.f);
  cvt_bf16_k<<<dim3(1024), dim3(256), 0, stream>>>(mlp_w2,  nullf, wb_m2,     NL*DM*DFFN/4, 0.f);

  const dim3 blk(256);
  const int fgrid = (SCUR/64) << shift;   // 64 q-tiles x nsplit
  for (int l = 0; l < NL; l++){
    // ---- self attention (fused QKV GEMM: N=768) ----
    ln_k<0><<<dim3(SCUR/4), blk, 0, stream>>>(x, ln1_w + l*DM, ln1_b + l*DM, (void*)t2b, SCUR);
    gemm_bt<0><<<dim3(3*DM/64, SCUR/64), blk, 0, stream>>>(t2b, wb_sa_qkv + (size_t)l*3*DM*DM, sa_b_qkv + (size_t)l*3*DM, (void*)qkvb, SCUR, 3*DM, DM);
    flash_k<<<dim3(fgrid), blk, 0, stream>>>(qkvb, 3*DM, qkvb + DM, 3*DM, qkvb + 2*DM, 3*DM,
                                             Opart, mpart, lpart, SCUR, SCUR/nsplit, shift);
    combine_k<<<dim3(SCUR), blk, 0, stream>>>(Opart, mpart, lpart, Ob, SCUR, nsplit);
    gemm_bt<2><<<dim3(DM/64, SCUR/64), blk, 0, stream>>>(Ob, wb_sa_o + (size_t)l*DM*DM, sa_b_o + l*DM, (void*)x, SCUR, DM, DM);

    // ---- cross attention ----
    ln_k<0><<<dim3(SCUR/4), blk, 0, stream>>>(x, ln2_w + l*DM, ln2_b + l*DM, (void*)t2b, SCUR);
    gemm_bt<0><<<dim3(DM/64, SCUR/64), blk, 0, stream>>>(t2b,   wb_ca_qkv + ((size_t)l*3+0)*DM*DM, ca_b_qkv + l*3*DM + 0*DM, (void*)Qb, SCUR, DM, DM);
    gemm_bt<0><<<dim3(DM/64, SMEM/64), blk, 0, stream>>>(memkb, wb_ca_qkv + ((size_t)l*3+1)*DM*DM, ca_b_qkv + l*3*DM + 1*DM, (void*)Kb, SMEM, DM, DM);
    gemm_bt<0><<<dim3(DM/64, SMEM/64), blk, 0, stream>>>(memb,  wb_ca_qkv + ((size_t)l*3+2)*DM*DM, ca_b_qkv + l*3*DM + 2*DM, (void*)Vb, SMEM, DM, DM);
    flash_k<<<dim3(fgrid), blk, 0, stream>>>(Qb, DM, Kb, DM, Vb, DM,
                                             Opart, mpart, lpart, SCUR, SMEM/nsplit, shift);
    combine_k<<<dim3(SCUR), blk, 0, stream>>>(Opart, mpart, lpart, Ob, SCUR, nsplit);
    gemm_bt<2><<<dim3(DM/64, SCUR/64), blk, 0, stream>>>(Ob, wb_ca_o + (size_t)l*DM*DM, ca_b_o + l*DM, (void*)x, SCUR, DM, DM);

    // ---- MLP ----
    ln_k<0><<<dim3(SCUR/4), blk, 0, stream>>>(x, ln3_w + l*DM, ln3_b + l*DM, (void*)t2b, SCUR);
    gemm_bt<1><<<dim3(DFFN/64, SCUR/64), blk, 0, stream>>>(t2b, wb_m1 + (size_t)l*DFFN*DM, mlp_b1 + l*DFFN, (void*)Hb, SCUR, DFFN, DM);
    gemm_bt<2><<<dim3(DM/64, SCUR/64), blk, 0, stream>>>(Hb, wb_m2 + (size_t)l*DM*DFFN, mlp_b2 + l*DM, (void*)x, SCUR, DM, DFFN);
  }

  ln_k<1><<<dim3(SCUR/4), blk, 0, stream>>>(x, norm_w, norm_b, d_out, SCUR);
}

// Round 8
// 2971.791 us; speedup vs baseline: 1.2486x; 1.2486x over previous
//
#include <hip/hip_runtime.h>
#include <hip/hip_bf16.h>

typedef unsigned short u16;
typedef unsigned int u32;
typedef __attribute__((ext_vector_type(8))) __bf16 bf16x8;
typedef __attribute__((ext_vector_type(4))) float f32x4;
typedef __attribute__((ext_vector_type(4))) u16 u16x4;
typedef __attribute__((ext_vector_type(8))) u16 u16x8;

#define SCUR 4096
#define SMEM 16384
#define DM   256
#define DFFN 2048
#define NL   4

__device__ __forceinline__ u16 f2b(float f){
  u32 i; __builtin_memcpy(&i, &f, 4);
  u32 r = (i + 0x7fffu + ((i >> 16) & 1u)) >> 16;
  return (u16)r;
}
__device__ __forceinline__ float b2f(u16 v){
  u32 i = ((u32)v) << 16; float f; __builtin_memcpy(&f, &i, 4); return f;
}

__device__ __forceinline__ f32x4 mfma16(bf16x8 a, bf16x8 b, f32x4 c){
  return __builtin_amdgcn_mfma_f32_16x16x32_bf16(a, b, c, 0, 0, 0);
}

// ---------------- elementwise prep ----------------

__global__ void axpy_k(const float* __restrict__ a, const float* __restrict__ b,
                       float s, float* __restrict__ o, int n4){
  int i = blockIdx.x * blockDim.x + threadIdx.x;
  int st = gridDim.x * blockDim.x;
  for (; i < n4; i += st){
    float4 x = ((const float4*)a)[i];
    float4 y = ((const float4*)b)[i];
    float4 r; r.x = x.x + s*y.x; r.y = x.y + s*y.y; r.z = x.z + s*y.z; r.w = x.w + s*y.w;
    ((float4*)o)[i] = r;
  }
}

__global__ void cvt_bf16_k(const float* __restrict__ a, const float* __restrict__ b,
                           u16* __restrict__ o, int n4, float s){
  int i = blockIdx.x * blockDim.x + threadIdx.x;
  int st = gridDim.x * blockDim.x;
  const bool hb = (b != nullptr);
  for (; i < n4; i += st){
    float4 x = ((const float4*)a)[i];
    if (hb){
      float4 y = ((const float4*)b)[i];
      x.x += s*y.x; x.y += s*y.y; x.z += s*y.z; x.w += s*y.w;
    }
    u16x4 r = { f2b(x.x), f2b(x.y), f2b(x.z), f2b(x.w) };
    ((u16x4*)o)[i] = r;
  }
}

// ---------------- layernorm ----------------
template<int OUTF32>
__global__ __launch_bounds__(256) void ln_k(const float* __restrict__ X,
    const float* __restrict__ g, const float* __restrict__ b,
    void* __restrict__ out, int rows){
  int row = blockIdx.x * 4 + (threadIdx.x >> 6);
  int lane = threadIdx.x & 63;
  if (row >= rows) return;
  const float4 v = *(const float4*)(X + (size_t)row*DM + lane*4);
  float s = v.x + v.y + v.z + v.w;
  for (int off = 1; off < 64; off <<= 1) s += __shfl_xor(s, off, 64);
  float mu = s * (1.f/256.f);
  float dx = v.x-mu, dy = v.y-mu, dz = v.z-mu, dw = v.w-mu;
  float q = dx*dx + dy*dy + dz*dz + dw*dw;
  for (int off = 1; off < 64; off <<= 1) q += __shfl_xor(q, off, 64);
  float rstd = rsqrtf(q * (1.f/256.f) + 1e-5f);
  const float4 gw = *(const float4*)(g + lane*4);
  const float4 gb = *(const float4*)(b + lane*4);
  float y0 = dx*rstd*gw.x + gb.x;
  float y1 = dy*rstd*gw.y + gb.y;
  float y2 = dz*rstd*gw.z + gb.z;
  float y3 = dw*rstd*gw.w + gb.w;
  if (OUTF32){
    float4 o; o.x=y0; o.y=y1; o.z=y2; o.w=y3;
    *(float4*)((float*)out + (size_t)row*DM + lane*4) = o;
  } else {
    u16x4 o = { f2b(y0), f2b(y1), f2b(y2), f2b(y3) };
    *(u16x4*)((u16*)out + (size_t)row*DM + lane*4) = o;
  }
}

// ---------------- GEMM: C[M][N] = A[M][K] * W[N][K]^T + bias ----------------
// EPI: 0 = bf16 out (bias[n]), 1 = relu->bf16 (bias[n]),
//      2 = += fp32 residual (bias[n]), 3 = bf16 out with bias[m] (V^T path)
template<int EPI>
__global__ __launch_bounds__(256) void gemm_bt(
    const u16* __restrict__ A, const u16* __restrict__ W,
    const float* __restrict__ bias, void* __restrict__ out,
    int M, int N, int K){
  __shared__ u16 a_sm[64*40];
  __shared__ u16 b_sm[64*40];
  const int tid = threadIdx.x;
  const int lane = tid & 63;
  const int w = tid >> 6;
  const int l16 = lane & 15, lg = lane >> 4;
  const int m0 = blockIdx.y * 64;
  const int n0 = blockIdx.x * 64;
  const int wr = (w >> 1) * 32, wc = (w & 1) * 32;
  f32x4 acc[2][2] = {};
  const int srow = tid >> 2, sch = tid & 3;
  const u16* Ag = A + (size_t)(m0 + srow) * K + sch * 8;
  const u16* Wg = W + (size_t)(n0 + srow) * K + sch * 8;
  for (int k0 = 0; k0 < K; k0 += 32){
    u16x8 av = *(const u16x8*)(Ag + k0);
    u16x8 wv = *(const u16x8*)(Wg + k0);
    __syncthreads();
    *(u16x8*)(a_sm + srow*40 + sch*8) = av;
    *(u16x8*)(b_sm + srow*40 + sch*8) = wv;
    __syncthreads();
    bf16x8 af0 = *(const bf16x8*)(a_sm + (wr      + l16)*40 + lg*8);
    bf16x8 af1 = *(const bf16x8*)(a_sm + (wr + 16 + l16)*40 + lg*8);
    bf16x8 bf0 = *(const bf16x8*)(b_sm + (wc      + l16)*40 + lg*8);
    bf16x8 bf1 = *(const bf16x8*)(b_sm + (wc + 16 + l16)*40 + lg*8);
    acc[0][0] = mfma16(af0, bf0, acc[0][0]);
    acc[0][1] = mfma16(af0, bf1, acc[0][1]);
    acc[1][0] = mfma16(af1, bf0, acc[1][0]);
    acc[1][1] = mfma16(af1, bf1, acc[1][1]);
  }
  for (int mi = 0; mi < 2; mi++)
    for (int ni = 0; ni < 2; ni++)
      for (int r = 0; r < 4; r++){
        int m = m0 + wr + mi*16 + lg*4 + r;
        int n = n0 + wc + ni*16 + l16;
        if (EPI == 3){
          float v = acc[mi][ni][r] + bias[m];
          ((u16*)out)[(size_t)m*N + n] = f2b(v);
        } else {
          float v = acc[mi][ni][r] + bias[n];
          if (EPI == 0)      ((u16*)out)[(size_t)m*N + n] = f2b(v);
          else if (EPI == 1) ((u16*)out)[(size_t)m*N + n] = f2b(v > 0.f ? v : 0.f);
          else               ((float*)out)[(size_t)m*N + n] += v;
        }
      }
}

// ---------------- flash attention (single head, hd=256) ----------------
// 256 threads = 4 waves, QBLK=64 (wave w owns 16 q-rows). NO block barriers:
// K and V^T fragments read directly from XCD-pinned L2; only per-wave 4KB
// P-tile LDS (lgkmcnt-local). grid = (Sq/64)<<shift; split = bid&(nsplit-1).
// V^T is [256][vts] row-major (produced transposed by the V-projection GEMM).
__global__ __launch_bounds__(256) void flash_k(
    const u16* __restrict__ Q, int qs,
    const u16* __restrict__ K, int kss,
    const u16* __restrict__ Vt, int vts,
    u16* __restrict__ Op, float* __restrict__ mp, float* __restrict__ lp,
    int Sq, int kvChunk, int shift){
  __shared__ u16 psm[4*1024];   // per-wave P tile 16x64, chunk swizzle
  const int bid = blockIdx.x;
  const int split = bid & ((1 << shift) - 1);
  const int qtile = bid >> shift;
  const int tid = threadIdx.x, lane = tid & 63, w = tid >> 6;
  const int l16 = lane & 15, lg = lane >> 4;
  const int qrow0 = qtile * 64 + w * 16;
  const int kv0 = split * kvChunk;
  const int nt = kvChunk >> 6;
  const u16* Kg = K + (size_t)kv0 * kss;
  const u16* Vg = Vt + kv0;                  // column offset into V^T

  bf16x8 qf[8];
  {
    const u16* qp = Q + (size_t)(qrow0 + l16) * qs + lg * 8;
    #pragma unroll
    for (int ks = 0; ks < 8; ks++) qf[ks] = *(const bf16x8*)(qp + ks*32);
  }
  f32x4 oa[16] = {};
  float mst[4] = {-1e30f, -1e30f, -1e30f, -1e30f};
  float lst[4] = {0.f, 0.f, 0.f, 0.f};

  for (int t = 0; t < nt; t++){
    // ---- S = (Q K^T)/16 : K straight from L2 ----
    const u16* Kt = Kg + (size_t)t * 64 * kss;
    f32x4 sa[4] = {};
    #pragma unroll
    for (int ks = 0; ks < 8; ks++){
      #pragma unroll
      for (int c = 0; c < 4; c++){
        bf16x8 kf = *(const bf16x8*)(Kt + (size_t)(c*16 + l16)*kss + ks*32 + lg*8);
        sa[c] = mfma16(qf[ks], kf, sa[c]);
      }
    }
    #pragma unroll
    for (int c = 0; c < 4; c++)
      #pragma unroll
      for (int r = 0; r < 4; r++) sa[c][r] *= 0.0625f;

    // ---- online softmax (16-lane group reduce; R5-proven) ----
    float alpha[4];
    #pragma unroll
    for (int r = 0; r < 4; r++){
      float mt = fmaxf(fmaxf(sa[0][r], sa[1][r]), fmaxf(sa[2][r], sa[3][r]));
      for (int off = 1; off < 16; off <<= 1) mt = fmaxf(mt, __shfl_xor(mt, off, 64));
      float mn = fmaxf(mst[r], mt);
      float al = __expf(mst[r] - mn);
      float rs = 0.f;
      #pragma unroll
      for (int c = 0; c < 4; c++){
        float pv = __expf(sa[c][r] - mn);
        sa[c][r] = pv;
        rs += pv;
      }
      for (int off = 1; off < 16; off <<= 1) rs += __shfl_xor(rs, off, 64);
      lst[r] = lst[r]*al + rs;
      mst[r] = mn;
      alpha[r] = al;
    }
    #pragma unroll
    for (int dc = 0; dc < 16; dc++)
      #pragma unroll
      for (int r = 0; r < 4; r++) oa[dc][r] *= alpha[r];

    // ---- write P (bf16) to per-wave LDS (same wave reads; no barrier) ----
    {
      u16* pw = psm + w*1024;
      #pragma unroll
      for (int c = 0; c < 4; c++)
        #pragma unroll
        for (int r = 0; r < 4; r++){
          int row = lg*4 + r;
          int col = c*16 + l16;
          int ch = col >> 3;
          int sc2 = ch ^ (row & 7);
          pw[row*64 + sc2*8 + (col & 7)] = f2b(sa[c][r]);
        }
    }

    // ---- O += P V : V^T fragments straight from L2 ----
    bf16x8 pf[2];
    {
      const u16* pb = psm + w*1024;
      #pragma unroll
      for (int ks2 = 0; ks2 < 2; ks2++){
        int ch = ks2*4 + lg;
        int sc2 = ch ^ (l16 & 7);
        pf[ks2] = *(const bf16x8*)(pb + l16*64 + sc2*8);
      }
    }
    const u16* Vtt = Vg + t*64;
    __builtin_amdgcn_s_setprio(1);
    #pragma unroll
    for (int dc = 0; dc < 16; dc++){
      #pragma unroll
      for (int ks2 = 0; ks2 < 2; ks2++){
        bf16x8 vf = *(const bf16x8*)(Vtt + (size_t)(dc*16 + l16)*vts + ks2*32 + lg*8);
        oa[dc] = mfma16(pf[ks2], vf, oa[dc]);
      }
    }
    __builtin_amdgcn_s_setprio(0);
  }

  // partials out (bf16): lane's oa[dc][r] = O[q=4*lg+r][d=dc*16+l16]
  u16* Obase = Op + (size_t)split * Sq * DM;
  #pragma unroll
  for (int dc = 0; dc < 16; dc++)
    #pragma unroll
    for (int r = 0; r < 4; r++){
      int q = qrow0 + lg*4 + r;
      int d = dc*16 + l16;
      Obase[(size_t)q*DM + d] = f2b(oa[dc][r]);
    }
  if (l16 == 0){
    #pragma unroll
    for (int r = 0; r < 4; r++){
      int q = qrow0 + lg*4 + r;
      mp[(size_t)split*Sq + q] = mst[r];
      lp[(size_t)split*Sq + q] = lst[r];
    }
  }
}

// combine KV-split partials (bf16) -> bf16 O
__global__ __launch_bounds__(256) void combine_k(const u16* __restrict__ Op,
    const float* __restrict__ mp, const float* __restrict__ lp,
    u16* __restrict__ Ob, int Sq, int nsplit){
  int q = blockIdx.x;
  int d = threadIdx.x;
  float mM = -1e30f;
  for (int i = 0; i < nsplit; i++) mM = fmaxf(mM, mp[(size_t)i*Sq + q]);
  float Ls = 0.f, acc = 0.f;
  for (int i = 0; i < nsplit; i++){
    float wgt = __expf(mp[(size_t)i*Sq + q] - mM);
    Ls  += lp[(size_t)i*Sq + q] * wgt;
    acc += wgt * b2f(Op[((size_t)i*Sq + q)*DM + d]);
  }
  Ob[(size_t)q*DM + d] = f2b(acc / Ls);
}

// ---------------- launch ----------------
extern "C" void kernel_launch(void* const* d_in, const int* in_sizes, int n_in,
                              void* d_out, int out_size, void* d_ws, size_t ws_size,
                              hipStream_t stream){
  (void)in_sizes; (void)n_in; (void)out_size;
  const float* curr       = (const float*)d_in[0];
  const float* memory     = (const float*)d_in[1];
  const float* curr_pos   = (const float*)d_in[2];
  const float* memory_pos = (const float*)d_in[3];
  const float* sa_w_qkv   = (const float*)d_in[4];
  const float* sa_b_qkv   = (const float*)d_in[5];
  const float* sa_w_o     = (const float*)d_in[6];
  const float* sa_b_o     = (const float*)d_in[7];
  const float* ca_w_qkv   = (const float*)d_in[8];
  const float* ca_b_qkv   = (const float*)d_in[9];
  const float* ca_w_o     = (const float*)d_in[10];
  const float* ca_b_o     = (const float*)d_in[11];
  const float* ln1_w = (const float*)d_in[12];
  const float* ln1_b = (const float*)d_in[13];
  const float* ln2_w = (const float*)d_in[14];
  const float* ln2_b = (const float*)d_in[15];
  const float* ln3_w = (const float*)d_in[16];
  const float* ln3_b = (const float*)d_in[17];
  const float* mlp_w1 = (const float*)d_in[18];
  const float* mlp_b1 = (const float*)d_in[19];
  const float* mlp_w2 = (const float*)d_in[20];
  const float* mlp_b2 = (const float*)d_in[21];
  const float* norm_w = (const float*)d_in[22];
  const float* norm_b = (const float*)d_in[23];

  const int nsplit = (ws_size >= (size_t)92*1024*1024) ? 16 : 8;
  const int shift  = (nsplit == 16) ? 4 : 3;

  char* wsp = (char*)d_ws;
  auto alloc = [&](size_t bytes)->void*{
    void* r = (void*)wsp; wsp += (bytes + 255) & ~(size_t)255; return r;
  };
  float* x     = (float*)alloc((size_t)SCUR*DM*4);
  u16*   t2b   = (u16*)  alloc((size_t)SCUR*DM*2);
  u16*   qkb   = (u16*)  alloc((size_t)SCUR*2*DM*2);   // self fused Q,K [S][512]; cross Q aliases
  u16*   vtsb  = (u16*)  alloc((size_t)DM*SCUR*2);     // self V^T [256][4096]
  u16*   Kb    = (u16*)  alloc((size_t)SMEM*DM*2);     // cross K [16384][256]
  u16*   vtcb  = (u16*)  alloc((size_t)DM*SMEM*2);     // cross V^T [256][16384]
  u16*   memkb = (u16*)  alloc((size_t)SMEM*DM*2);
  u16*   memb  = (u16*)  alloc((size_t)SMEM*DM*2);
  // union: MLP hidden (16MB) aliases bf16 attention partials (nsplit*2MB)
  size_t uni_bytes = (size_t)SCUR*DFFN*2;
  size_t op_bytes  = (size_t)nsplit*SCUR*DM*2;
  char*  uni   = (char*) alloc(uni_bytes > op_bytes ? uni_bytes : op_bytes);
  u16*   Hb    = (u16*)uni;
  u16*   Opart = (u16*)uni;
  float* mpart = (float*)alloc((size_t)16*SCUR*4);
  float* lpart = (float*)alloc((size_t)16*SCUR*4);
  u16* wb_sa_qkv = (u16*)alloc((size_t)NL*3*DM*DM*2);
  u16* wb_sa_o   = (u16*)alloc((size_t)NL*DM*DM*2);
  u16* wb_ca_qkv = (u16*)alloc((size_t)NL*3*DM*DM*2);
  u16* wb_ca_o   = (u16*)alloc((size_t)NL*DM*DM*2);
  u16* wb_m1     = (u16*)alloc((size_t)NL*DFFN*DM*2);
  u16* wb_m2     = (u16*)alloc((size_t)NL*DM*DFFN*2);

  u16* Ob = t2b;      // alias: t2b dead once the pre-flash GEMMs have consumed it
  u16* Qb = qkb;      // alias: qkb free during cross-attention

  const float* nullf = nullptr;

  axpy_k<<<dim3(512), dim3(256), 0, stream>>>(curr, curr_pos, 0.1f, x, SCUR*DM/4);
  cvt_bf16_k<<<dim3(1024), dim3(256), 0, stream>>>(memory, memory_pos, memkb, SMEM*DM/4, 1.0f);
  cvt_bf16_k<<<dim3(1024), dim3(256), 0, stream>>>(memory, nullf, memb, SMEM*DM/4, 0.f);
  cvt_bf16_k<<<dim3(512), dim3(256), 0, stream>>>(sa_w_qkv, nullf, wb_sa_qkv, NL*3*DM*DM/4, 0.f);
  cvt_bf16_k<<<dim3(256), dim3(256), 0, stream>>>(sa_w_o,   nullf, wb_sa_o,   NL*DM*DM/4,   0.f);
  cvt_bf16_k<<<dim3(512), dim3(256), 0, stream>>>(ca_w_qkv, nullf, wb_ca_qkv, NL*3*DM*DM/4, 0.f);
  cvt_bf16_k<<<dim3(256), dim3(256), 0, stream>>>(ca_w_o,   nullf, wb_ca_o,   NL*DM*DM/4,   0.f);
  cvt_bf16_k<<<dim3(1024), dim3(256), 0, stream>>>(mlp_w1,  nullf, wb_m1,     NL*DFFN*DM/4, 0.f);
  cvt_bf16_k<<<dim3(1024), dim3(256), 0, stream>>>(mlp_w2,  nullf, wb_m2,     NL*DM*DFFN/4, 0.f);

  const dim3 blk(256);
  const int fgrid = (SCUR/64) << shift;   // 64 q-tiles x nsplit
  for (int l = 0; l < NL; l++){
    // ---- self attention ----
    ln_k<0><<<dim3(SCUR/4), blk, 0, stream>>>(x, ln1_w + l*DM, ln1_b + l*DM, (void*)t2b, SCUR);
    // fused Q,K GEMM (N=512)
    gemm_bt<0><<<dim3(2*DM/64, SCUR/64), blk, 0, stream>>>(t2b, wb_sa_qkv + (size_t)l*3*DM*DM, sa_b_qkv + (size_t)l*3*DM, (void*)qkb, SCUR, 2*DM, DM);
    // V^T GEMM: Vt[d][key] = Wv @ t2b^T + bv[d]  (M=256, N=4096)
    gemm_bt<3><<<dim3(SCUR/64, DM/64), blk, 0, stream>>>(wb_sa_qkv + ((size_t)l*3+2)*DM*DM, t2b, sa_b_qkv + (size_t)l*3*DM + 2*DM, (void*)vtsb, DM, SCUR, DM);
    flash_k<<<dim3(fgrid), blk, 0, stream>>>(qkb, 2*DM, qkb + DM, 2*DM, vtsb, SCUR,
                                             Opart, mpart, lpart, SCUR, SCUR/nsplit, shift);
    combine_k<<<dim3(SCUR), blk, 0, stream>>>(Opart, mpart, lpart, Ob, SCUR, nsplit);
    gemm_bt<2><<<dim3(DM/64, SCUR/64), blk, 0, stream>>>(Ob, wb_sa_o + (size_t)l*DM*DM, sa_b_o + l*DM, (void*)x, SCUR, DM, DM);

    // ---- cross attention ----
    ln_k<0><<<dim3(SCUR/4), blk, 0, stream>>>(x, ln2_w + l*DM, ln2_b + l*DM, (void*)t2b, SCUR);
    gemm_bt<0><<<dim3(DM/64, SCUR/64), blk, 0, stream>>>(t2b,   wb_ca_qkv + ((size_t)l*3+0)*DM*DM, ca_b_qkv + l*3*DM + 0*DM, (void*)Qb, SCUR, DM, DM);
    gemm_bt<0><<<dim3(DM/64, SMEM/64), blk, 0, stream>>>(memkb, wb_ca_qkv + ((size_t)l*3+1)*DM*DM, ca_b_qkv + l*3*DM + 1*DM, (void*)Kb, SMEM, DM, DM);
    // V^T GEMM: Vt[d][key] = Wv @ memb^T + bv[d]  (M=256, N=16384)
    gemm_bt<3><<<dim3(SMEM/64, DM/64), blk, 0, stream>>>(wb_ca_qkv + ((size_t)l*3+2)*DM*DM, memb, ca_b_qkv + (size_t)l*3*DM + 2*DM, (void*)vtcb, DM, SMEM, DM);
    flash_k<<<dim3(fgrid), blk, 0, stream>>>(Qb, DM, Kb, DM, vtcb, SMEM,
                                             Opart, mpart, lpart, SCUR, SMEM/nsplit, shift);
    combine_k<<<dim3(SCUR), blk, 0, stream>>>(Opart, mpart, lpart, Ob, SCUR, nsplit);
    gemm_bt<2><<<dim3(DM/64, SCUR/64), blk, 0, stream>>>(Ob, wb_ca_o + (size_t)l*DM*DM, ca_b_o + l*DM, (void*)x, SCUR, DM, DM);

    // ---- MLP ----
    ln_k<0><<<dim3(SCUR/4), blk, 0, stream>>>(x, ln3_w + l*DM, ln3_b + l*DM, (void*)t2b, SCUR);
    gemm_bt<1><<<dim3(DFFN/64, SCUR/64), blk, 0, stream>>>(t2b, wb_m1 + (size_t)l*DFFN*DM, mlp_b1 + l*DFFN, (void*)Hb, SCUR, DFFN, DM);
    gemm_bt<2><<<dim3(DM/64, SCUR/64), blk, 0, stream>>>(Hb, wb_m2 + (size_t)l*DM*DFFN, mlp_b2 + l*DM, (void*)x, SCUR, DM, DFFN);
  }

  ln_k<1><<<dim3(SCUR/4), blk, 0, stream>>>(x, norm_w, norm_b, d_out, SCUR);
}

// Round 9
// 2114.832 us; speedup vs baseline: 1.7545x; 1.4052x over previous
//
#include <hip/hip_runtime.h>
#include <hip/hip_bf16.h>

typedef unsigned short u16;
typedef unsigned int u32;
typedef __attribute__((ext_vector_type(8))) __bf16 bf16x8;
typedef __attribute__((ext_vector_type(4))) float f32x4;
typedef __attribute__((ext_vector_type(4))) u16 u16x4;
typedef __attribute__((ext_vector_type(8))) u16 u16x8;

#define SCUR 4096
#define SMEM 16384
#define DM   256
#define DFFN 2048
#define NL   4

__device__ __forceinline__ u16 f2b(float f){
  u32 i; __builtin_memcpy(&i, &f, 4);
  u32 r = (i + 0x7fffu + ((i >> 16) & 1u)) >> 16;
  return (u16)r;
}
__device__ __forceinline__ float b2f(u16 v){
  u32 i = ((u32)v) << 16; float f; __builtin_memcpy(&f, &i, 4); return f;
}

__device__ __forceinline__ f32x4 mfma16(bf16x8 a, bf16x8 b, f32x4 c){
  return __builtin_amdgcn_mfma_f32_16x16x32_bf16(a, b, c, 0, 0, 0);
}

// ---------------- elementwise prep ----------------

__global__ void axpy_k(const float* __restrict__ a, const float* __restrict__ b,
                       float s, float* __restrict__ o, int n4){
  int i = blockIdx.x * blockDim.x + threadIdx.x;
  int st = gridDim.x * blockDim.x;
  for (; i < n4; i += st){
    float4 x = ((const float4*)a)[i];
    float4 y = ((const float4*)b)[i];
    float4 r; r.x = x.x + s*y.x; r.y = x.y + s*y.y; r.z = x.z + s*y.z; r.w = x.w + s*y.w;
    ((float4*)o)[i] = r;
  }
}

__global__ void cvt_bf16_k(const float* __restrict__ a, const float* __restrict__ b,
                           u16* __restrict__ o, int n4, float s){
  int i = blockIdx.x * blockDim.x + threadIdx.x;
  int st = gridDim.x * blockDim.x;
  const bool hb = (b != nullptr);
  for (; i < n4; i += st){
    float4 x = ((const float4*)a)[i];
    if (hb){
      float4 y = ((const float4*)b)[i];
      x.x += s*y.x; x.y += s*y.y; x.z += s*y.z; x.w += s*y.w;
    }
    u16x4 r = { f2b(x.x), f2b(x.y), f2b(x.z), f2b(x.w) };
    ((u16x4*)o)[i] = r;
  }
}

// ---------------- layernorm ----------------
template<int OUTF32>
__global__ __launch_bounds__(256) void ln_k(const float* __restrict__ X,
    const float* __restrict__ g, const float* __restrict__ b,
    void* __restrict__ out, int rows){
  int row = blockIdx.x * 4 + (threadIdx.x >> 6);
  int lane = threadIdx.x & 63;
  if (row >= rows) return;
  const float4 v = *(const float4*)(X + (size_t)row*DM + lane*4);
  float s = v.x + v.y + v.z + v.w;
  for (int off = 1; off < 64; off <<= 1) s += __shfl_xor(s, off, 64);
  float mu = s * (1.f/256.f);
  float dx = v.x-mu, dy = v.y-mu, dz = v.z-mu, dw = v.w-mu;
  float q = dx*dx + dy*dy + dz*dz + dw*dw;
  for (int off = 1; off < 64; off <<= 1) q += __shfl_xor(q, off, 64);
  float rstd = rsqrtf(q * (1.f/256.f) + 1e-5f);
  const float4 gw = *(const float4*)(g + lane*4);
  const float4 gb = *(const float4*)(b + lane*4);
  float y0 = dx*rstd*gw.x + gb.x;
  float y1 = dy*rstd*gw.y + gb.y;
  float y2 = dz*rstd*gw.z + gb.z;
  float y3 = dw*rstd*gw.w + gb.w;
  if (OUTF32){
    float4 o; o.x=y0; o.y=y1; o.z=y2; o.w=y3;
    *(float4*)((float*)out + (size_t)row*DM + lane*4) = o;
  } else {
    u16x4 o = { f2b(y0), f2b(y1), f2b(y2), f2b(y3) };
    *(u16x4*)((u16*)out + (size_t)row*DM + lane*4) = o;
  }
}

// ---------------- GEMM: C[M][N] = A[M][K] * W[N][K]^T (+ bias) ----------------
// EPI: 0 bf16+bias[n], 1 relu->bf16+bias[n], 2 +=fp32 residual +bias[n],
//      3 bf16+bias[m] (V^T), 4 bf16 no bias
template<int EPI>
__global__ __launch_bounds__(256) void gemm_bt(
    const u16* __restrict__ A, int lda, const u16* __restrict__ W, int ldw,
    const float* __restrict__ bias, void* __restrict__ out, int ldc,
    int M, int N, int K){
  __shared__ u16 a_sm[64*40];
  __shared__ u16 b_sm[64*40];
  const int tid = threadIdx.x;
  const int lane = tid & 63;
  const int w = tid >> 6;
  const int l16 = lane & 15, lg = lane >> 4;
  const int m0 = blockIdx.y * 64;
  const int n0 = blockIdx.x * 64;
  const int wr = (w >> 1) * 32, wc = (w & 1) * 32;
  f32x4 acc[2][2] = {};
  const int srow = tid >> 2, sch = tid & 3;
  const u16* Ag = A + (size_t)(m0 + srow) * lda + sch * 8;
  const u16* Wg = W + (size_t)(n0 + srow) * ldw + sch * 8;
  for (int k0 = 0; k0 < K; k0 += 32){
    u16x8 av = *(const u16x8*)(Ag + k0);
    u16x8 wv = *(const u16x8*)(Wg + k0);
    __syncthreads();
    *(u16x8*)(a_sm + srow*40 + sch*8) = av;
    *(u16x8*)(b_sm + srow*40 + sch*8) = wv;
    __syncthreads();
    bf16x8 af0 = *(const bf16x8*)(a_sm + (wr      + l16)*40 + lg*8);
    bf16x8 af1 = *(const bf16x8*)(a_sm + (wr + 16 + l16)*40 + lg*8);
    bf16x8 bf0 = *(const bf16x8*)(b_sm + (wc      + l16)*40 + lg*8);
    bf16x8 bf1 = *(const bf16x8*)(b_sm + (wc + 16 + l16)*40 + lg*8);
    acc[0][0] = mfma16(af0, bf0, acc[0][0]);
    acc[0][1] = mfma16(af0, bf1, acc[0][1]);
    acc[1][0] = mfma16(af1, bf0, acc[1][0]);
    acc[1][1] = mfma16(af1, bf1, acc[1][1]);
  }
  for (int mi = 0; mi < 2; mi++)
    for (int ni = 0; ni < 2; ni++)
      for (int r = 0; r < 4; r++){
        int m = m0 + wr + mi*16 + lg*4 + r;
        int n = n0 + wc + ni*16 + l16;
        float v = acc[mi][ni][r];
        if (EPI == 3)      v += bias[m];
        else if (EPI != 4) v += bias[n];
        if (EPI == 2)      ((float*)out)[(size_t)m*ldc + n] += v;
        else if (EPI == 1) ((u16*)out)[(size_t)m*ldc + n] = f2b(v > 0.f ? v : 0.f);
        else               ((u16*)out)[(size_t)m*ldc + n] = f2b(v);
      }
}

// ---------------- row softmax (in-place, bf16) ----------------
// one block (256 thr) per row of NC*2048 cols; scale applied pre-exp
template<int NC>
__global__ __launch_bounds__(256) void softmax_k(u16* __restrict__ S, int ld, float scale){
  __shared__ float red[8];
  const int tid = threadIdx.x, w = tid >> 6;
  u16* rp = S + (size_t)blockIdx.x * ld + tid*8;
  u16x8 v[NC];
  #pragma unroll
  for (int c = 0; c < NC; c++) v[c] = *(const u16x8*)(rp + c*2048);
  float m = -1e30f;
  #pragma unroll
  for (int c = 0; c < NC; c++)
    #pragma unroll
    for (int e = 0; e < 8; e++) m = fmaxf(m, b2f(v[c][e]));
  #pragma unroll
  for (int off = 1; off < 64; off <<= 1) m = fmaxf(m, __shfl_xor(m, off, 64));
  if ((tid & 63) == 0) red[w] = m;
  __syncthreads();
  float mm = fmaxf(fmaxf(red[0], red[1]), fmaxf(red[2], red[3])) * scale;
  float s = 0.f;
  #pragma unroll
  for (int c = 0; c < NC; c++)
    #pragma unroll
    for (int e = 0; e < 8; e++){
      float p = __expf(b2f(v[c][e]) * scale - mm);
      s += p;
      v[c][e] = f2b(p);
    }
  #pragma unroll
  for (int off = 1; off < 64; off <<= 1) s += __shfl_xor(s, off, 64);
  if ((tid & 63) == 0) red[4 + w] = s;
  __syncthreads();
  float inv = 1.f / (red[4] + red[5] + red[6] + red[7]);
  #pragma unroll
  for (int c = 0; c < NC; c++){
    #pragma unroll
    for (int e = 0; e < 8; e++) v[c][e] = f2b(b2f(v[c][e]) * inv);
    *(u16x8*)(rp + c*2048) = v[c];
  }
}

// ---------------- launch ----------------
extern "C" void kernel_launch(void* const* d_in, const int* in_sizes, int n_in,
                              void* d_out, int out_size, void* d_ws, size_t ws_size,
                              hipStream_t stream){
  (void)in_sizes; (void)n_in; (void)out_size;
  const float* curr       = (const float*)d_in[0];
  const float* memory     = (const float*)d_in[1];
  const float* curr_pos   = (const float*)d_in[2];
  const float* memory_pos = (const float*)d_in[3];
  const float* sa_w_qkv   = (const float*)d_in[4];
  const float* sa_b_qkv   = (const float*)d_in[5];
  const float* sa_w_o     = (const float*)d_in[6];
  const float* sa_b_o     = (const float*)d_in[7];
  const float* ca_w_qkv   = (const float*)d_in[8];
  const float* ca_b_qkv   = (const float*)d_in[9];
  const float* ca_w_o     = (const float*)d_in[10];
  const float* ca_b_o     = (const float*)d_in[11];
  const float* ln1_w = (const float*)d_in[12];
  const float* ln1_b = (const float*)d_in[13];
  const float* ln2_w = (const float*)d_in[14];
  const float* ln2_b = (const float*)d_in[15];
  const float* ln3_w = (const float*)d_in[16];
  const float* ln3_b = (const float*)d_in[17];
  const float* mlp_w1 = (const float*)d_in[18];
  const float* mlp_b1 = (const float*)d_in[19];
  const float* mlp_w2 = (const float*)d_in[20];
  const float* mlp_b2 = (const float*)d_in[21];
  const float* norm_w = (const float*)d_in[22];
  const float* norm_b = (const float*)d_in[23];

  char* wsp = (char*)d_ws;
  auto alloc = [&](size_t bytes)->void*{
    void* r = (void*)wsp; wsp += (bytes + 255) & ~(size_t)255; return r;
  };
  float* x     = (float*)alloc((size_t)SCUR*DM*4);
  u16*   t2b   = (u16*)  alloc((size_t)SCUR*DM*2);
  u16*   qkb   = (u16*)  alloc((size_t)SCUR*2*DM*2);   // self fused Q,K [S][512]; cross Q aliases
  u16*   vtsb  = (u16*)  alloc((size_t)DM*SCUR*2);     // self V^T [256][4096]
  u16*   Kb    = (u16*)  alloc((size_t)SMEM*DM*2);     // cross K [16384][256]
  u16*   vtcb  = (u16*)  alloc((size_t)DM*SMEM*2);     // cross V^T [256][16384]
  u16*   memkb = (u16*)  alloc((size_t)SMEM*DM*2);
  u16*   memb  = (u16*)  alloc((size_t)SMEM*DM*2);
  u16*   Hb    = (u16*)  alloc((size_t)SCUR*DFFN*2);   // MLP hidden; S-fallback alias
  u16* wb_sa_qkv = (u16*)alloc((size_t)NL*3*DM*DM*2);
  u16* wb_sa_o   = (u16*)alloc((size_t)NL*DM*DM*2);
  u16* wb_ca_qkv = (u16*)alloc((size_t)NL*3*DM*DM*2);
  u16* wb_ca_o   = (u16*)alloc((size_t)NL*DM*DM*2);
  u16* wb_m1     = (u16*)alloc((size_t)NL*DFFN*DM*2);
  u16* wb_m2     = (u16*)alloc((size_t)NL*DM*DFFN*2);

  // ---- S buffer: as large as the workspace allows ----
  size_t used  = (size_t)(wsp - (char*)d_ws);
  size_t avail = (ws_size > used) ? (ws_size - used) : 0;
  const size_t rowb = (size_t)SMEM * 2;                 // 32 KB per cross row
  u16* Sbuf;
  int CHc;                                              // cross q-chunk rows
  if (avail >= (size_t)SCUR * rowb){
    CHc = SCUR;
    Sbuf = (u16*)alloc((size_t)SCUR * rowb);
  } else {
    size_t ch = (avail / rowb) & ~(size_t)63;
    if (ch >= 512){
      CHc = (int)(ch > SCUR ? SCUR : ch);
      Sbuf = (u16*)alloc((size_t)CHc * rowb);
    } else {
      CHc = 512;                                        // 512*32KB = 16MB fits Hb
      Sbuf = Hb;
    }
  }
  size_t scap = (size_t)CHc * rowb;
  int CHs = (int)(scap / ((size_t)SCUR*2));             // self chunk rows
  if (CHs > SCUR) CHs = SCUR;
  CHs &= ~63;

  u16* Ob = t2b;      // alias: t2b consumed by projections before PV writes it
  u16* Qb = qkb;      // alias: qkb free during cross-attention

  const float* nullf = nullptr;
  const float sc = 0.0625f;  // 1/sqrt(256)

  axpy_k<<<dim3(512), dim3(256), 0, stream>>>(curr, curr_pos, 0.1f, x, SCUR*DM/4);
  cvt_bf16_k<<<dim3(1024), dim3(256), 0, stream>>>(memory, memory_pos, memkb, SMEM*DM/4, 1.0f);
  cvt_bf16_k<<<dim3(1024), dim3(256), 0, stream>>>(memory, nullf, memb, SMEM*DM/4, 0.f);
  cvt_bf16_k<<<dim3(512), dim3(256), 0, stream>>>(sa_w_qkv, nullf, wb_sa_qkv, NL*3*DM*DM/4, 0.f);
  cvt_bf16_k<<<dim3(256), dim3(256), 0, stream>>>(sa_w_o,   nullf, wb_sa_o,   NL*DM*DM/4,   0.f);
  cvt_bf16_k<<<dim3(512), dim3(256), 0, stream>>>(ca_w_qkv, nullf, wb_ca_qkv, NL*3*DM*DM/4, 0.f);
  cvt_bf16_k<<<dim3(256), dim3(256), 0, stream>>>(ca_w_o,   nullf, wb_ca_o,   NL*DM*DM/4,   0.f);
  cvt_bf16_k<<<dim3(1024), dim3(256), 0, stream>>>(mlp_w1,  nullf, wb_m1,     NL*DFFN*DM/4, 0.f);
  cvt_bf16_k<<<dim3(1024), dim3(256), 0, stream>>>(mlp_w2,  nullf, wb_m2,     NL*DM*DFFN/4, 0.f);

  const dim3 blk(256);
  for (int l = 0; l < NL; l++){
    // ---- self attention ----
    ln_k<0><<<dim3(SCUR/4), blk, 0, stream>>>(x, ln1_w + l*DM, ln1_b + l*DM, (void*)t2b, SCUR);
    // fused Q,K projection (N=512)
    gemm_bt<0><<<dim3(512/64, SCUR/64), blk, 0, stream>>>(t2b, DM, wb_sa_qkv + (size_t)l*3*DM*DM, DM,
        sa_b_qkv + (size_t)l*3*DM, (void*)qkb, 512, SCUR, 512, DM);
    // V^T projection: Vt[d][q] (M=256, N=4096)
    gemm_bt<3><<<dim3(SCUR/64, DM/64), blk, 0, stream>>>(wb_sa_qkv + ((size_t)l*3+2)*DM*DM, DM, t2b, DM,
        sa_b_qkv + (size_t)l*3*DM + 2*DM, (void*)vtsb, SCUR, DM, SCUR, DM);
    for (int c = 0; c < SCUR; c += CHs){
      int Mc = (SCUR - c) < CHs ? (SCUR - c) : CHs;
      gemm_bt<4><<<dim3(SCUR/64, Mc/64), blk, 0, stream>>>(qkb + (size_t)c*512, 512, qkb + DM, 512,
          nullf, (void*)Sbuf, SCUR, Mc, SCUR, DM);
      softmax_k<2><<<dim3(Mc), blk, 0, stream>>>(Sbuf, SCUR, sc);
      gemm_bt<4><<<dim3(DM/64, Mc/64), blk, 0, stream>>>(Sbuf, SCUR, vtsb, SCUR,
          nullf, (void*)(Ob + (size_t)c*DM), DM, Mc, DM, SCUR);
    }
    gemm_bt<2><<<dim3(DM/64, SCUR/64), blk, 0, stream>>>(Ob, DM, wb_sa_o + (size_t)l*DM*DM, DM,
        sa_b_o + l*DM, (void*)x, DM, SCUR, DM, DM);

    // ---- cross attention ----
    ln_k<0><<<dim3(SCUR/4), blk, 0, stream>>>(x, ln2_w + l*DM, ln2_b + l*DM, (void*)t2b, SCUR);
    gemm_bt<0><<<dim3(DM/64, SCUR/64), blk, 0, stream>>>(t2b, DM, wb_ca_qkv + ((size_t)l*3+0)*DM*DM, DM,
        ca_b_qkv + l*3*DM + 0*DM, (void*)Qb, DM, SCUR, DM, DM);
    gemm_bt<0><<<dim3(DM/64, SMEM/64), blk, 0, stream>>>(memkb, DM, wb_ca_qkv + ((size_t)l*3+1)*DM*DM, DM,
        ca_b_qkv + l*3*DM + 1*DM, (void*)Kb, DM, SMEM, DM, DM);
    // V^T projection: Vt[d][key] (M=256, N=16384)
    gemm_bt<3><<<dim3(SMEM/64, DM/64), blk, 0, stream>>>(wb_ca_qkv + ((size_t)l*3+2)*DM*DM, DM, memb, DM,
        ca_b_qkv + (size_t)l*3*DM + 2*DM, (void*)vtcb, SMEM, DM, SMEM, DM);
    for (int c = 0; c < SCUR; c += CHc){
      int Mc = (SCUR - c) < CHc ? (SCUR - c) : CHc;
      gemm_bt<4><<<dim3(SMEM/64, Mc/64), blk, 0, stream>>>(Qb + (size_t)c*DM, DM, Kb, DM,
          nullf, (void*)Sbuf, SMEM, Mc, SMEM, DM);
      softmax_k<8><<<dim3(Mc), blk, 0, stream>>>(Sbuf, SMEM, sc);
      gemm_bt<4><<<dim3(DM/64, Mc/64), blk, 0, stream>>>(Sbuf, SMEM, vtcb, SMEM,
          nullf, (void*)(Ob + (size_t)c*DM), DM, Mc, DM, SMEM);
    }
    gemm_bt<2><<<dim3(DM/64, SCUR/64), blk, 0, stream>>>(Ob, DM, wb_ca_o + (size_t)l*DM*DM, DM,
        ca_b_o + l*DM, (void*)x, DM, SCUR, DM, DM);

    // ---- MLP ----
    ln_k<0><<<dim3(SCUR/4), blk, 0, stream>>>(x, ln3_w + l*DM, ln3_b + l*DM, (void*)t2b, SCUR);
    gemm_bt<1><<<dim3(DFFN/64, SCUR/64), blk, 0, stream>>>(t2b, DM, wb_m1 + (size_t)l*DFFN*DM, DM,
        mlp_b1 + l*DFFN, (void*)Hb, DFFN, SCUR, DFFN, DM);
    gemm_bt<2><<<dim3(DM/64, SCUR/64), blk, 0, stream>>>(Hb, DFFN, wb_m2 + (size_t)l*DM*DFFN, DFFN,
        mlp_b2 + l*DM, (void*)x, DM, SCUR, DM, DFFN);
  }

  ln_k<1><<<dim3(SCUR/4), blk, 0, stream>>>(x, norm_w, norm_b, d_out, SCUR);
}

// Round 10
// 1706.038 us; speedup vs baseline: 2.1749x; 1.2396x over previous
//
#include <hip/hip_runtime.h>
#include <hip/hip_bf16.h>

typedef unsigned short u16;
typedef unsigned int u32;
typedef __attribute__((ext_vector_type(8))) __bf16 bf16x8;
typedef __attribute__((ext_vector_type(4))) float f32x4;
typedef __attribute__((ext_vector_type(4))) u16 u16x4;
typedef __attribute__((ext_vector_type(8))) u16 u16x8;

#define SCUR 4096
#define SMEM 16384
#define DM   256
#define DFFN 2048
#define NL   4

__device__ __forceinline__ u16 f2b(float f){
  u32 i; __builtin_memcpy(&i, &f, 4);
  u32 r = (i + 0x7fffu + ((i >> 16) & 1u)) >> 16;
  return (u16)r;
}
__device__ __forceinline__ float b2f(u16 v){
  u32 i = ((u32)v) << 16; float f; __builtin_memcpy(&f, &i, 4); return f;
}

__device__ __forceinline__ f32x4 mfma16(bf16x8 a, bf16x8 b, f32x4 c){
  return __builtin_amdgcn_mfma_f32_16x16x32_bf16(a, b, c, 0, 0, 0);
}

// ---------------- elementwise prep ----------------

__global__ void axpy_k(const float* __restrict__ a, const float* __restrict__ b,
                       float s, float* __restrict__ o, int n4){
  int i = blockIdx.x * blockDim.x + threadIdx.x;
  int st = gridDim.x * blockDim.x;
  for (; i < n4; i += st){
    float4 x = ((const float4*)a)[i];
    float4 y = ((const float4*)b)[i];
    float4 r; r.x = x.x + s*y.x; r.y = x.y + s*y.y; r.z = x.z + s*y.z; r.w = x.w + s*y.w;
    ((float4*)o)[i] = r;
  }
}

__global__ void cvt_bf16_k(const float* __restrict__ a, const float* __restrict__ b,
                           u16* __restrict__ o, int n4, float s){
  int i = blockIdx.x * blockDim.x + threadIdx.x;
  int st = gridDim.x * blockDim.x;
  const bool hb = (b != nullptr);
  for (; i < n4; i += st){
    float4 x = ((const float4*)a)[i];
    if (hb){
      float4 y = ((const float4*)b)[i];
      x.x += s*y.x; x.y += s*y.y; x.z += s*y.z; x.w += s*y.w;
    }
    u16x4 r = { f2b(x.x), f2b(x.y), f2b(x.z), f2b(x.w) };
    ((u16x4*)o)[i] = r;
  }
}

// ---------------- layernorm ----------------
template<int OUTF32>
__global__ __launch_bounds__(256) void ln_k(const float* __restrict__ X,
    const float* __restrict__ g, const float* __restrict__ b,
    void* __restrict__ out, int rows){
  int row = blockIdx.x * 4 + (threadIdx.x >> 6);
  int lane = threadIdx.x & 63;
  if (row >= rows) return;
  const float4 v = *(const float4*)(X + (size_t)row*DM + lane*4);
  float s = v.x + v.y + v.z + v.w;
  for (int off = 1; off < 64; off <<= 1) s += __shfl_xor(s, off, 64);
  float mu = s * (1.f/256.f);
  float dx = v.x-mu, dy = v.y-mu, dz = v.z-mu, dw = v.w-mu;
  float q = dx*dx + dy*dy + dz*dz + dw*dw;
  for (int off = 1; off < 64; off <<= 1) q += __shfl_xor(q, off, 64);
  float rstd = rsqrtf(q * (1.f/256.f) + 1e-5f);
  const float4 gw = *(const float4*)(g + lane*4);
  const float4 gb = *(const float4*)(b + lane*4);
  float y0 = dx*rstd*gw.x + gb.x;
  float y1 = dy*rstd*gw.y + gb.y;
  float y2 = dz*rstd*gw.z + gb.z;
  float y3 = dw*rstd*gw.w + gb.w;
  if (OUTF32){
    float4 o; o.x=y0; o.y=y1; o.z=y2; o.w=y3;
    *(float4*)((float*)out + (size_t)row*DM + lane*4) = o;
  } else {
    u16x4 o = { f2b(y0), f2b(y1), f2b(y2), f2b(y3) };
    *(u16x4*)((u16*)out + (size_t)row*DM + lane*4) = o;
  }
}

// ---------------- GEMM: C[M][N] = A[M][K] * W[N][K]^T (+ bias) ----------------
// EPI: 0 bf16+bias[n], 1 relu->bf16+bias[n], 2 +=fp32 residual +bias[n],
//      3 bf16+bias[m] (V^T), 4 bf16 no bias
// K-split: blockIdx.z selects K-chunk [z*K, (z+1)*K); output += z*zout elements.
// Software-pipelined: tile t+1 global loads issue right after tile t LDS write.
template<int EPI>
__global__ __launch_bounds__(256) void gemm_bt(
    const u16* __restrict__ A, int lda, const u16* __restrict__ W, int ldw,
    const float* __restrict__ bias, void* __restrict__ out, int ldc,
    int M, int N, int K, size_t zout){
  __shared__ u16 a_sm[64*40];
  __shared__ u16 b_sm[64*40];
  const int tid = threadIdx.x;
  const int lane = tid & 63;
  const int w = tid >> 6;
  const int l16 = lane & 15, lg = lane >> 4;
  const int m0 = blockIdx.y * 64;
  const int n0 = blockIdx.x * 64;
  const int wr = (w >> 1) * 32, wc = (w & 1) * 32;
  f32x4 acc[2][2] = {};
  const int srow = tid >> 2, sch = tid & 3;
  const int koff = blockIdx.z * K;
  const u16* Ag = A + (size_t)(m0 + srow) * lda + sch * 8 + koff;
  const u16* Wg = W + (size_t)(n0 + srow) * ldw + sch * 8 + koff;
  u16x8 av = *(const u16x8*)(Ag);
  u16x8 wv = *(const u16x8*)(Wg);
  for (int k0 = 0; k0 < K; k0 += 32){
    __syncthreads();
    *(u16x8*)(a_sm + srow*40 + sch*8) = av;
    *(u16x8*)(b_sm + srow*40 + sch*8) = wv;
    if (k0 + 32 < K){
      av = *(const u16x8*)(Ag + k0 + 32);
      wv = *(const u16x8*)(Wg + k0 + 32);
    }
    __syncthreads();
    bf16x8 af0 = *(const bf16x8*)(a_sm + (wr      + l16)*40 + lg*8);
    bf16x8 af1 = *(const bf16x8*)(a_sm + (wr + 16 + l16)*40 + lg*8);
    bf16x8 bf0 = *(const bf16x8*)(b_sm + (wc      + l16)*40 + lg*8);
    bf16x8 bf1 = *(const bf16x8*)(b_sm + (wc + 16 + l16)*40 + lg*8);
    acc[0][0] = mfma16(af0, bf0, acc[0][0]);
    acc[0][1] = mfma16(af0, bf1, acc[0][1]);
    acc[1][0] = mfma16(af1, bf0, acc[1][0]);
    acc[1][1] = mfma16(af1, bf1, acc[1][1]);
  }
  for (int mi = 0; mi < 2; mi++)
    for (int ni = 0; ni < 2; ni++)
      for (int r = 0; r < 4; r++){
        int m = m0 + wr + mi*16 + lg*4 + r;
        int n = n0 + wc + ni*16 + l16;
        float v = acc[mi][ni][r];
        if (EPI == 3)      v += bias[m];
        else if (EPI != 4) v += bias[n];
        if (EPI == 2)      ((float*)out + blockIdx.z*zout)[(size_t)m*ldc + n] += v;
        else if (EPI == 1) ((u16*)out + blockIdx.z*zout)[(size_t)m*ldc + n] = f2b(v > 0.f ? v : 0.f);
        else               ((u16*)out + blockIdx.z*zout)[(size_t)m*ldc + n] = f2b(v);
      }
}

// ---------------- K-split partial reduction ----------------
// P: [ks][M][256] bf16 partials
__global__ __launch_bounds__(256) void reduce_pv_k(const u16* __restrict__ P,
    u16* __restrict__ O, int M, int ks){
  int m = blockIdx.x, d = threadIdx.x;
  const size_t st = (size_t)M * 256;
  float s = 0.f;
  for (int i = 0; i < ks; i++) s += b2f(P[(size_t)i*st + (size_t)m*256 + d]);
  O[(size_t)m*256 + d] = f2b(s);
}
__global__ __launch_bounds__(256) void reduce_res_k(const u16* __restrict__ P,
    const float* __restrict__ bias, float* __restrict__ X, int M, int ks){
  int m = blockIdx.x, d = threadIdx.x;
  const size_t st = (size_t)M * 256;
  float s = bias[d];
  for (int i = 0; i < ks; i++) s += b2f(P[(size_t)i*st + (size_t)m*256 + d]);
  X[(size_t)m*256 + d] += s;
}

// ---------------- row softmax (in-place, bf16) ----------------
template<int NC>
__global__ __launch_bounds__(256) void softmax_k(u16* __restrict__ S, int ld, float scale){
  __shared__ float red[8];
  const int tid = threadIdx.x, w = tid >> 6;
  u16* rp = S + (size_t)blockIdx.x * ld + tid*8;
  u16x8 v[NC];
  #pragma unroll
  for (int c = 0; c < NC; c++) v[c] = *(const u16x8*)(rp + c*2048);
  float m = -1e30f;
  #pragma unroll
  for (int c = 0; c < NC; c++)
    #pragma unroll
    for (int e = 0; e < 8; e++) m = fmaxf(m, b2f(v[c][e]));
  #pragma unroll
  for (int off = 1; off < 64; off <<= 1) m = fmaxf(m, __shfl_xor(m, off, 64));
  if ((tid & 63) == 0) red[w] = m;
  __syncthreads();
  float mm = fmaxf(fmaxf(red[0], red[1]), fmaxf(red[2], red[3])) * scale;
  float s = 0.f;
  #pragma unroll
  for (int c = 0; c < NC; c++)
    #pragma unroll
    for (int e = 0; e < 8; e++){
      float p = __expf(b2f(v[c][e]) * scale - mm);
      s += p;
      v[c][e] = f2b(p);
    }
  #pragma unroll
  for (int off = 1; off < 64; off <<= 1) s += __shfl_xor(s, off, 64);
  if ((tid & 63) == 0) red[4 + w] = s;
  __syncthreads();
  float inv = 1.f / (red[4] + red[5] + red[6] + red[7]);
  #pragma unroll
  for (int c = 0; c < NC; c++){
    #pragma unroll
    for (int e = 0; e < 8; e++) v[c][e] = f2b(b2f(v[c][e]) * inv);
    *(u16x8*)(rp + c*2048) = v[c];
  }
}

// ---------------- launch ----------------
extern "C" void kernel_launch(void* const* d_in, const int* in_sizes, int n_in,
                              void* d_out, int out_size, void* d_ws, size_t ws_size,
                              hipStream_t stream){
  (void)in_sizes; (void)n_in; (void)out_size;
  const float* curr       = (const float*)d_in[0];
  const float* memory     = (const float*)d_in[1];
  const float* curr_pos   = (const float*)d_in[2];
  const float* memory_pos = (const float*)d_in[3];
  const float* sa_w_qkv   = (const float*)d_in[4];
  const float* sa_b_qkv   = (const float*)d_in[5];
  const float* sa_w_o     = (const float*)d_in[6];
  const float* sa_b_o     = (const float*)d_in[7];
  const float* ca_w_qkv   = (const float*)d_in[8];
  const float* ca_b_qkv   = (const float*)d_in[9];
  const float* ca_w_o     = (const float*)d_in[10];
  const float* ca_b_o     = (const float*)d_in[11];
  const float* ln1_w = (const float*)d_in[12];
  const float* ln1_b = (const float*)d_in[13];
  const float* ln2_w = (const float*)d_in[14];
  const float* ln2_b = (const float*)d_in[15];
  const float* ln3_w = (const float*)d_in[16];
  const float* ln3_b = (const float*)d_in[17];
  const float* mlp_w1 = (const float*)d_in[18];
  const float* mlp_b1 = (const float*)d_in[19];
  const float* mlp_w2 = (const float*)d_in[20];
  const float* mlp_b2 = (const float*)d_in[21];
  const float* norm_w = (const float*)d_in[22];
  const float* norm_b = (const float*)d_in[23];

  char* wsp = (char*)d_ws;
  auto alloc = [&](size_t bytes)->void*{
    void* r = (void*)wsp; wsp += (bytes + 255) & ~(size_t)255; return r;
  };
  float* x     = (float*)alloc((size_t)SCUR*DM*4);
  u16*   t2b   = (u16*)  alloc((size_t)SCUR*DM*2);
  u16*   qkb   = (u16*)  alloc((size_t)SCUR*2*DM*2);   // self fused Q,K [S][512]; cross Q aliases
  u16*   vtsb  = (u16*)  alloc((size_t)DM*SCUR*2);     // self V^T [256][4096]
  u16*   Kb    = (u16*)  alloc((size_t)SMEM*DM*2);     // cross K [16384][256]
  u16*   vtcb  = (u16*)  alloc((size_t)DM*SMEM*2);     // cross V^T [256][16384]
  u16*   memkb = (u16*)  alloc((size_t)SMEM*DM*2);
  u16*   memb  = (u16*)  alloc((size_t)SMEM*DM*2);
  u16*   Hb    = (u16*)  alloc((size_t)SCUR*DFFN*2);   // MLP hidden; S-fallback alias
  u16*   Ppart = (u16*)  alloc((size_t)8*SCUR*DM*2);   // K-split partials (16MB max)
  u16* wb_sa_qkv = (u16*)alloc((size_t)NL*3*DM*DM*2);
  u16* wb_sa_o   = (u16*)alloc((size_t)NL*DM*DM*2);
  u16* wb_ca_qkv = (u16*)alloc((size_t)NL*3*DM*DM*2);
  u16* wb_ca_o   = (u16*)alloc((size_t)NL*DM*DM*2);
  u16* wb_m1     = (u16*)alloc((size_t)NL*DFFN*DM*2);
  u16* wb_m2     = (u16*)alloc((size_t)NL*DM*DFFN*2);

  // ---- S buffer: as large as the workspace allows ----
  size_t used  = (size_t)(wsp - (char*)d_ws);
  size_t avail = (ws_size > used) ? (ws_size - used) : 0;
  const size_t rowb = (size_t)SMEM * 2;                 // 32 KB per cross row
  u16* Sbuf;
  int CHc;                                              // cross q-chunk rows
  if (avail >= (size_t)SCUR * rowb){
    CHc = SCUR;
    Sbuf = (u16*)alloc((size_t)SCUR * rowb);
  } else {
    size_t ch = (avail / rowb) & ~(size_t)63;
    if (ch >= 512){
      CHc = (int)(ch > SCUR ? SCUR : ch);
      Sbuf = (u16*)alloc((size_t)CHc * rowb);
    } else {
      CHc = 512;                                        // 512*32KB = 16MB fits Hb
      Sbuf = Hb;
    }
  }
  size_t scap = (size_t)CHc * rowb;
  int CHs = (int)(scap / ((size_t)SCUR*2));             // self chunk rows
  if (CHs > SCUR) CHs = SCUR;
  CHs &= ~63;

  u16* Ob = t2b;      // alias: t2b consumed by projections before PV writes it
  u16* Qb = qkb;      // alias: qkb free during cross-attention

  const float* nullf = nullptr;
  const float sc = 0.0625f;  // 1/sqrt(256)

  axpy_k<<<dim3(512), dim3(256), 0, stream>>>(curr, curr_pos, 0.1f, x, SCUR*DM/4);
  cvt_bf16_k<<<dim3(1024), dim3(256), 0, stream>>>(memory, memory_pos, memkb, SMEM*DM/4, 1.0f);
  cvt_bf16_k<<<dim3(1024), dim3(256), 0, stream>>>(memory, nullf, memb, SMEM*DM/4, 0.f);
  cvt_bf16_k<<<dim3(512), dim3(256), 0, stream>>>(sa_w_qkv, nullf, wb_sa_qkv, NL*3*DM*DM/4, 0.f);
  cvt_bf16_k<<<dim3(256), dim3(256), 0, stream>>>(sa_w_o,   nullf, wb_sa_o,   NL*DM*DM/4,   0.f);
  cvt_bf16_k<<<dim3(512), dim3(256), 0, stream>>>(ca_w_qkv, nullf, wb_ca_qkv, NL*3*DM*DM/4, 0.f);
  cvt_bf16_k<<<dim3(256), dim3(256), 0, stream>>>(ca_w_o,   nullf, wb_ca_o,   NL*DM*DM/4,   0.f);
  cvt_bf16_k<<<dim3(1024), dim3(256), 0, stream>>>(mlp_w1,  nullf, wb_m1,     NL*DFFN*DM/4, 0.f);
  cvt_bf16_k<<<dim3(1024), dim3(256), 0, stream>>>(mlp_w2,  nullf, wb_m2,     NL*DM*DFFN/4, 0.f);

  const dim3 blk(256);
  for (int l = 0; l < NL; l++){
    // ---- self attention ----
    ln_k<0><<<dim3(SCUR/4), blk, 0, stream>>>(x, ln1_w + l*DM, ln1_b + l*DM, (void*)t2b, SCUR);
    gemm_bt<0><<<dim3(512/64, SCUR/64), blk, 0, stream>>>(t2b, DM, wb_sa_qkv + (size_t)l*3*DM*DM, DM,
        sa_b_qkv + (size_t)l*3*DM, (void*)qkb, 512, SCUR, 512, DM, 0);
    gemm_bt<3><<<dim3(SCUR/64, DM/64), blk, 0, stream>>>(wb_sa_qkv + ((size_t)l*3+2)*DM*DM, DM, t2b, DM,
        sa_b_qkv + (size_t)l*3*DM + 2*DM, (void*)vtsb, SCUR, DM, SCUR, DM, 0);
    for (int c = 0; c < SCUR; c += CHs){
      int Mc = (SCUR - c) < CHs ? (SCUR - c) : CHs;
      gemm_bt<4><<<dim3(SCUR/64, Mc/64), blk, 0, stream>>>(qkb + (size_t)c*512, 512, qkb + DM, 512,
          nullf, (void*)Sbuf, SCUR, Mc, SCUR, DM, 0);
      softmax_k<2><<<dim3(Mc), blk, 0, stream>>>(Sbuf, SCUR, sc);
      // PV with K-split 4 (K=1024 per split)
      gemm_bt<4><<<dim3(DM/64, Mc/64, 4), blk, 0, stream>>>(Sbuf, SCUR, vtsb, SCUR,
          nullf, (void*)Ppart, DM, Mc, DM, SCUR/4, (size_t)Mc*DM);
      reduce_pv_k<<<dim3(Mc), blk, 0, stream>>>(Ppart, Ob + (size_t)c*DM, Mc, 4);
    }
    gemm_bt<2><<<dim3(DM/64, SCUR/64), blk, 0, stream>>>(Ob, DM, wb_sa_o + (size_t)l*DM*DM, DM,
        sa_b_o + l*DM, (void*)x, DM, SCUR, DM, DM, 0);

    // ---- cross attention ----
    ln_k<0><<<dim3(SCUR/4), blk, 0, stream>>>(x, ln2_w + l*DM, ln2_b + l*DM, (void*)t2b, SCUR);
    gemm_bt<0><<<dim3(DM/64, SCUR/64), blk, 0, stream>>>(t2b, DM, wb_ca_qkv + ((size_t)l*3+0)*DM*DM, DM,
        ca_b_qkv + l*3*DM + 0*DM, (void*)Qb, DM, SCUR, DM, DM, 0);
    gemm_bt<0><<<dim3(DM/64, SMEM/64), blk, 0, stream>>>(memkb, DM, wb_ca_qkv + ((size_t)l*3+1)*DM*DM, DM,
        ca_b_qkv + l*3*DM + 1*DM, (void*)Kb, DM, SMEM, DM, DM, 0);
    gemm_bt<3><<<dim3(SMEM/64, DM/64), blk, 0, stream>>>(wb_ca_qkv + ((size_t)l*3+2)*DM*DM, DM, memb, DM,
        ca_b_qkv + (size_t)l*3*DM + 2*DM, (void*)vtcb, SMEM, DM, SMEM, DM, 0);
    for (int c = 0; c < SCUR; c += CHc){
      int Mc = (SCUR - c) < CHc ? (SCUR - c) : CHc;
      gemm_bt<4><<<dim3(SMEM/64, Mc/64), blk, 0, stream>>>(Qb + (size_t)c*DM, DM, Kb, DM,
          nullf, (void*)Sbuf, SMEM, Mc, SMEM, DM, 0);
      softmax_k<8><<<dim3(Mc), blk, 0, stream>>>(Sbuf, SMEM, sc);
      // PV with K-split 8 (K=2048 per split)
      gemm_bt<4><<<dim3(DM/64, Mc/64, 8), blk, 0, stream>>>(Sbuf, SMEM, vtcb, SMEM,
          nullf, (void*)Ppart, DM, Mc, DM, SMEM/8, (size_t)Mc*DM);
      reduce_pv_k<<<dim3(Mc), blk, 0, stream>>>(Ppart, Ob + (size_t)c*DM, Mc, 8);
    }
    gemm_bt<2><<<dim3(DM/64, SCUR/64), blk, 0, stream>>>(Ob, DM, wb_ca_o + (size_t)l*DM*DM, DM,
        ca_b_o + l*DM, (void*)x, DM, SCUR, DM, DM, 0);

    // ---- MLP ----
    ln_k<0><<<dim3(SCUR/4), blk, 0, stream>>>(x, ln3_w + l*DM, ln3_b + l*DM, (void*)t2b, SCUR);
    gemm_bt<1><<<dim3(DFFN/64, SCUR/64), blk, 0, stream>>>(t2b, DM, wb_m1 + (size_t)l*DFFN*DM, DM,
        mlp_b1 + l*DFFN, (void*)Hb, DFFN, SCUR, DFFN, DM, 0);
    // down-proj with K-split 4 (K=512 per split), then bias+residual reduce
    gemm_bt<4><<<dim3(DM/64, SCUR/64, 4), blk, 0, stream>>>(Hb, DFFN, wb_m2 + (size_t)l*DM*DFFN, DFFN,
        nullf, (void*)Ppart, DM, SCUR, DM, DFFN/4, (size_t)SCUR*DM);
    reduce_res_k<<<dim3(SCUR), blk, 0, stream>>>(Ppart, mlp_b2 + l*DM, x, SCUR, 4);
  }

  ln_k<1><<<dim3(SCUR/4), blk, 0, stream>>>(x, norm_w, norm_b, d_out, SCUR);
}

// Round 11
// 1335.640 us; speedup vs baseline: 2.7781x; 1.2773x over previous
//
#include <hip/hip_runtime.h>
#include <hip/hip_bf16.h>

typedef unsigned short u16;
typedef unsigned int u32;
typedef __attribute__((ext_vector_type(8))) __bf16 bf16x8;
typedef __attribute__((ext_vector_type(4))) float f32x4;
typedef __attribute__((ext_vector_type(4))) u16 u16x4;
typedef __attribute__((ext_vector_type(8))) u16 u16x8;

#define SCUR 4096
#define SMEM 16384
#define DM   256
#define DFFN 2048
#define NL   4

__device__ __forceinline__ u16 f2b(float f){
  u32 i; __builtin_memcpy(&i, &f, 4);
  u32 r = (i + 0x7fffu + ((i >> 16) & 1u)) >> 16;
  return (u16)r;
}
__device__ __forceinline__ float b2f(u16 v){
  u32 i = ((u32)v) << 16; float f; __builtin_memcpy(&f, &i, 4); return f;
}

__device__ __forceinline__ f32x4 mfma16(bf16x8 a, bf16x8 b, f32x4 c){
  return __builtin_amdgcn_mfma_f32_16x16x32_bf16(a, b, c, 0, 0, 0);
}

// ---------------- elementwise prep ----------------

__global__ void axpy_k(const float* __restrict__ a, const float* __restrict__ b,
                       float s, float* __restrict__ o, int n4){
  int i = blockIdx.x * blockDim.x + threadIdx.x;
  int st = gridDim.x * blockDim.x;
  for (; i < n4; i += st){
    float4 x = ((const float4*)a)[i];
    float4 y = ((const float4*)b)[i];
    float4 r; r.x = x.x + s*y.x; r.y = x.y + s*y.y; r.z = x.z + s*y.z; r.w = x.w + s*y.w;
    ((float4*)o)[i] = r;
  }
}

__global__ void cvt_bf16_k(const float* __restrict__ a, const float* __restrict__ b,
                           u16* __restrict__ o, int n4, float s){
  int i = blockIdx.x * blockDim.x + threadIdx.x;
  int st = gridDim.x * blockDim.x;
  const bool hb = (b != nullptr);
  for (; i < n4; i += st){
    float4 x = ((const float4*)a)[i];
    if (hb){
      float4 y = ((const float4*)b)[i];
      x.x += s*y.x; x.y += s*y.y; x.z += s*y.z; x.w += s*y.w;
    }
    u16x4 r = { f2b(x.x), f2b(x.y), f2b(x.z), f2b(x.w) };
    ((u16x4*)o)[i] = r;
  }
}

// ---------------- layernorm ----------------
template<int OUTF32>
__global__ __launch_bounds__(256) void ln_k(const float* __restrict__ X,
    const float* __restrict__ g, const float* __restrict__ b,
    void* __restrict__ out, int rows){
  int row = blockIdx.x * 4 + (threadIdx.x >> 6);
  int lane = threadIdx.x & 63;
  if (row >= rows) return;
  const float4 v = *(const float4*)(X + (size_t)row*DM + lane*4);
  float s = v.x + v.y + v.z + v.w;
  for (int off = 1; off < 64; off <<= 1) s += __shfl_xor(s, off, 64);
  float mu = s * (1.f/256.f);
  float dx = v.x-mu, dy = v.y-mu, dz = v.z-mu, dw = v.w-mu;
  float q = dx*dx + dy*dy + dz*dz + dw*dw;
  for (int off = 1; off < 64; off <<= 1) q += __shfl_xor(q, off, 64);
  float rstd = rsqrtf(q * (1.f/256.f) + 1e-5f);
  const float4 gw = *(const float4*)(g + lane*4);
  const float4 gb = *(const float4*)(b + lane*4);
  float y0 = dx*rstd*gw.x + gb.x;
  float y1 = dy*rstd*gw.y + gb.y;
  float y2 = dz*rstd*gw.z + gb.z;
  float y3 = dw*rstd*gw.w + gb.w;
  if (OUTF32){
    float4 o; o.x=y0; o.y=y1; o.z=y2; o.w=y3;
    *(float4*)((float*)out + (size_t)row*DM + lane*4) = o;
  } else {
    u16x4 o = { f2b(y0), f2b(y1), f2b(y2), f2b(y3) };
    *(u16x4*)((u16*)out + (size_t)row*DM + lane*4) = o;
  }
}

// ---------------- GEMM: C[M][N] = A[M][K] * W[N][K]^T (+ bias) ----------------
// EPI: 0 bf16+bias[n], 1 relu->bf16+bias[n], 2 +=fp32 residual +bias[n],
//      3 bf16+bias[m] (V^T), 4 bf16 no bias
template<int EPI>
__global__ __launch_bounds__(256) void gemm_bt(
    const u16* __restrict__ A, int lda, const u16* __restrict__ W, int ldw,
    const float* __restrict__ bias, void* __restrict__ out, int ldc,
    int M, int N, int K){
  __shared__ u16 a_sm[64*40];
  __shared__ u16 b_sm[64*40];
  const int tid = threadIdx.x;
  const int lane = tid & 63;
  const int w = tid >> 6;
  const int l16 = lane & 15, lg = lane >> 4;
  const int m0 = blockIdx.y * 64;
  const int n0 = blockIdx.x * 64;
  const int wr = (w >> 1) * 32, wc = (w & 1) * 32;
  f32x4 acc[2][2] = {};
  const int srow = tid >> 2, sch = tid & 3;
  const u16* Ag = A + (size_t)(m0 + srow) * lda + sch * 8;
  const u16* Wg = W + (size_t)(n0 + srow) * ldw + sch * 8;
  u16x8 av = *(const u16x8*)(Ag);
  u16x8 wv = *(const u16x8*)(Wg);
  for (int k0 = 0; k0 < K; k0 += 32){
    __syncthreads();
    *(u16x8*)(a_sm + srow*40 + sch*8) = av;
    *(u16x8*)(b_sm + srow*40 + sch*8) = wv;
    if (k0 + 32 < K){
      av = *(const u16x8*)(Ag + k0 + 32);
      wv = *(const u16x8*)(Wg + k0 + 32);
    }
    __syncthreads();
    bf16x8 af0 = *(const bf16x8*)(a_sm + (wr      + l16)*40 + lg*8);
    bf16x8 af1 = *(const bf16x8*)(a_sm + (wr + 16 + l16)*40 + lg*8);
    bf16x8 bf0 = *(const bf16x8*)(b_sm + (wc      + l16)*40 + lg*8);
    bf16x8 bf1 = *(const bf16x8*)(b_sm + (wc + 16 + l16)*40 + lg*8);
    acc[0][0] = mfma16(af0, bf0, acc[0][0]);
    acc[0][1] = mfma16(af0, bf1, acc[0][1]);
    acc[1][0] = mfma16(af1, bf0, acc[1][0]);
    acc[1][1] = mfma16(af1, bf1, acc[1][1]);
  }
  for (int mi = 0; mi < 2; mi++)
    for (int ni = 0; ni < 2; ni++)
      for (int r = 0; r < 4; r++){
        int m = m0 + wr + mi*16 + lg*4 + r;
        int n = n0 + wc + ni*16 + l16;
        float v = acc[mi][ni][r];
        if (EPI == 3)      v += bias[m];
        else if (EPI != 4) v += bias[n];
        if (EPI == 2)      ((float*)out)[(size_t)m*ldc + n] += v;
        else if (EPI == 1) ((u16*)out)[(size_t)m*ldc + n] = f2b(v > 0.f ? v : 0.f);
        else               ((u16*)out)[(size_t)m*ldc + n] = f2b(v);
      }
}

// ---------------- wide-N GEMM for PV / down-proj (N = 256 fixed) ----------------
// C_partial[z][M][256] = A[M][koff..koff+K] * W[256][koff..koff+K]^T  (bf16 out)
// One block computes a full 64x256 stripe -> A read exactly once per z-slice.
// grid (M/64, ksplit); wave w owns cols [w*64, w*64+64).
__global__ __launch_bounds__(256) void gemm_pv(
    const u16* __restrict__ A, int lda, const u16* __restrict__ W, int ldw,
    u16* __restrict__ out, int M, int K){
  __shared__ u16 a_sm[64*40];
  __shared__ u16 b_sm[256*40];
  const int tid = threadIdx.x, lane = tid & 63, w = tid >> 6;
  const int l16 = lane & 15, lg = lane >> 4;
  const int m0 = blockIdx.x * 64;
  const int koff = blockIdx.y * K;
  f32x4 acc[4][4] = {};
  const int srow = tid >> 2, sch = tid & 3;
  const u16* Ag = A + (size_t)(m0 + srow) * lda + sch * 8 + koff;
  const u16* Wg = W + (size_t)srow * ldw + sch * 8 + koff;
  u16x8 av  = *(const u16x8*)(Ag);
  u16x8 wv0 = *(const u16x8*)(Wg);
  u16x8 wv1 = *(const u16x8*)(Wg + (size_t)64*ldw);
  u16x8 wv2 = *(const u16x8*)(Wg + (size_t)128*ldw);
  u16x8 wv3 = *(const u16x8*)(Wg + (size_t)192*ldw);
  for (int k0 = 0; k0 < K; k0 += 32){
    __syncthreads();
    *(u16x8*)(a_sm + srow*40 + sch*8) = av;
    *(u16x8*)(b_sm + srow*40 + sch*8) = wv0;
    *(u16x8*)(b_sm + (srow+64)*40 + sch*8) = wv1;
    *(u16x8*)(b_sm + (srow+128)*40 + sch*8) = wv2;
    *(u16x8*)(b_sm + (srow+192)*40 + sch*8) = wv3;
    if (k0 + 32 < K){
      av  = *(const u16x8*)(Ag + k0 + 32);
      wv0 = *(const u16x8*)(Wg + k0 + 32);
      wv1 = *(const u16x8*)(Wg + (size_t)64*ldw + k0 + 32);
      wv2 = *(const u16x8*)(Wg + (size_t)128*ldw + k0 + 32);
      wv3 = *(const u16x8*)(Wg + (size_t)192*ldw + k0 + 32);
    }
    __syncthreads();
    bf16x8 af[4], bf[4];
    #pragma unroll
    for (int i = 0; i < 4; i++)
      af[i] = *(const bf16x8*)(a_sm + (i*16 + l16)*40 + lg*8);
    #pragma unroll
    for (int i = 0; i < 4; i++)
      bf[i] = *(const bf16x8*)(b_sm + (w*64 + i*16 + l16)*40 + lg*8);
    #pragma unroll
    for (int mi = 0; mi < 4; mi++)
      #pragma unroll
      for (int ni = 0; ni < 4; ni++)
        acc[mi][ni] = mfma16(af[mi], bf[ni], acc[mi][ni]);
  }
  u16* op = out + (size_t)blockIdx.y * M * 256;
  #pragma unroll
  for (int mi = 0; mi < 4; mi++)
    #pragma unroll
    for (int ni = 0; ni < 4; ni++)
      #pragma unroll
      for (int r = 0; r < 4; r++){
        int m = m0 + mi*16 + lg*4 + r;
        int n = w*64 + ni*16 + l16;
        op[(size_t)m*256 + n] = f2b(acc[mi][ni][r]);
      }
}

// ---------------- K-split partial reduction ----------------
__global__ __launch_bounds__(256) void reduce_pv_k(const u16* __restrict__ P,
    u16* __restrict__ O, int M, int ks){
  int m = blockIdx.x, d = threadIdx.x;
  const size_t st = (size_t)M * 256;
  float s = 0.f;
  for (int i = 0; i < ks; i++) s += b2f(P[(size_t)i*st + (size_t)m*256 + d]);
  O[(size_t)m*256 + d] = f2b(s);
}
__global__ __launch_bounds__(256) void reduce_res_k(const u16* __restrict__ P,
    const float* __restrict__ bias, float* __restrict__ X, int M, int ks){
  int m = blockIdx.x, d = threadIdx.x;
  const size_t st = (size_t)M * 256;
  float s = bias[d];
  for (int i = 0; i < ks; i++) s += b2f(P[(size_t)i*st + (size_t)m*256 + d]);
  X[(size_t)m*256 + d] += s;
}

// ---------------- row softmax (in-place, bf16) ----------------
template<int NC>
__global__ __launch_bounds__(256) void softmax_k(u16* __restrict__ S, int ld, float scale){
  __shared__ float red[8];
  const int tid = threadIdx.x, w = tid >> 6;
  u16* rp = S + (size_t)blockIdx.x * ld + tid*8;
  u16x8 v[NC];
  #pragma unroll
  for (int c = 0; c < NC; c++) v[c] = *(const u16x8*)(rp + c*2048);
  float m = -1e30f;
  #pragma unroll
  for (int c = 0; c < NC; c++)
    #pragma unroll
    for (int e = 0; e < 8; e++) m = fmaxf(m, b2f(v[c][e]));
  #pragma unroll
  for (int off = 1; off < 64; off <<= 1) m = fmaxf(m, __shfl_xor(m, off, 64));
  if ((tid & 63) == 0) red[w] = m;
  __syncthreads();
  float mm = fmaxf(fmaxf(red[0], red[1]), fmaxf(red[2], red[3])) * scale;
  float s = 0.f;
  #pragma unroll
  for (int c = 0; c < NC; c++)
    #pragma unroll
    for (int e = 0; e < 8; e++){
      float p = __expf(b2f(v[c][e]) * scale - mm);
      s += p;
      v[c][e] = f2b(p);
    }
  #pragma unroll
  for (int off = 1; off < 64; off <<= 1) s += __shfl_xor(s, off, 64);
  if ((tid & 63) == 0) red[4 + w] = s;
  __syncthreads();
  float inv = 1.f / (red[4] + red[5] + red[6] + red[7]);
  #pragma unroll
  for (int c = 0; c < NC; c++){
    #pragma unroll
    for (int e = 0; e < 8; e++) v[c][e] = f2b(b2f(v[c][e]) * inv);
    *(u16x8*)(rp + c*2048) = v[c];
  }
}

// ---------------- launch ----------------
extern "C" void kernel_launch(void* const* d_in, const int* in_sizes, int n_in,
                              void* d_out, int out_size, void* d_ws, size_t ws_size,
                              hipStream_t stream){
  (void)in_sizes; (void)n_in; (void)out_size;
  const float* curr       = (const float*)d_in[0];
  const float* memory     = (const float*)d_in[1];
  const float* curr_pos   = (const float*)d_in[2];
  const float* memory_pos = (const float*)d_in[3];
  const float* sa_w_qkv   = (const float*)d_in[4];
  const float* sa_b_qkv   = (const float*)d_in[5];
  const float* sa_w_o     = (const float*)d_in[6];
  const float* sa_b_o     = (const float*)d_in[7];
  const float* ca_w_qkv   = (const float*)d_in[8];
  const float* ca_b_qkv   = (const float*)d_in[9];
  const float* ca_w_o     = (const float*)d_in[10];
  const float* ca_b_o     = (const float*)d_in[11];
  const float* ln1_w = (const float*)d_in[12];
  const float* ln1_b = (const float*)d_in[13];
  const float* ln2_w = (const float*)d_in[14];
  const float* ln2_b = (const float*)d_in[15];
  const float* ln3_w = (const float*)d_in[16];
  const float* ln3_b = (const float*)d_in[17];
  const float* mlp_w1 = (const float*)d_in[18];
  const float* mlp_b1 = (const float*)d_in[19];
  const float* mlp_w2 = (const float*)d_in[20];
  const float* mlp_b2 = (const float*)d_in[21];
  const float* norm_w = (const float*)d_in[22];
  const float* norm_b = (const float*)d_in[23];

  char* wsp = (char*)d_ws;
  auto alloc = [&](size_t bytes)->void*{
    void* r = (void*)wsp; wsp += (bytes + 255) & ~(size_t)255; return r;
  };
  float* x     = (float*)alloc((size_t)SCUR*DM*4);
  u16*   t2b   = (u16*)  alloc((size_t)SCUR*DM*2);
  u16*   qkb   = (u16*)  alloc((size_t)SCUR*2*DM*2);   // self fused Q,K [S][512]; cross Q aliases
  u16*   vtsb  = (u16*)  alloc((size_t)DM*SCUR*2);     // self V^T [256][4096]
  u16*   Kb    = (u16*)  alloc((size_t)SMEM*DM*2);     // cross K [16384][256]
  u16*   vtcb  = (u16*)  alloc((size_t)DM*SMEM*2);     // cross V^T [256][16384]
  u16*   memkb = (u16*)  alloc((size_t)SMEM*DM*2);
  u16*   memb  = (u16*)  alloc((size_t)SMEM*DM*2);
  u16*   Hb    = (u16*)  alloc((size_t)SCUR*DFFN*2);   // MLP hidden; S-fallback alias
  u16*   Ppart = (u16*)  alloc((size_t)8*SCUR*DM*2);   // K-split partials (16MB max)
  u16* wb_sa_qkv = (u16*)alloc((size_t)NL*3*DM*DM*2);
  u16* wb_sa_o   = (u16*)alloc((size_t)NL*DM*DM*2);
  u16* wb_ca_qkv = (u16*)alloc((size_t)NL*3*DM*DM*2);
  u16* wb_ca_o   = (u16*)alloc((size_t)NL*DM*DM*2);
  u16* wb_m1     = (u16*)alloc((size_t)NL*DFFN*DM*2);
  u16* wb_m2     = (u16*)alloc((size_t)NL*DM*DFFN*2);

  // ---- S buffer: as large as the workspace allows ----
  size_t used  = (size_t)(wsp - (char*)d_ws);
  size_t avail = (ws_size > used) ? (ws_size - used) : 0;
  const size_t rowb = (size_t)SMEM * 2;                 // 32 KB per cross row
  u16* Sbuf;
  int CHc;                                              // cross q-chunk rows
  if (avail >= (size_t)SCUR * rowb){
    CHc = SCUR;
    Sbuf = (u16*)alloc((size_t)SCUR * rowb);
  } else {
    size_t ch = (avail / rowb) & ~(size_t)63;
    if (ch >= 512){
      CHc = (int)(ch > SCUR ? SCUR : ch);
      Sbuf = (u16*)alloc((size_t)CHc * rowb);
    } else {
      CHc = 512;                                        // 512*32KB = 16MB fits Hb
      Sbuf = Hb;
    }
  }
  size_t scap = (size_t)CHc * rowb;
  int CHs = (int)(scap / ((size_t)SCUR*2));             // self chunk rows
  if (CHs > SCUR) CHs = SCUR;
  CHs &= ~63;

  u16* Ob = t2b;      // alias: t2b consumed by projections before PV writes it
  u16* Qb = qkb;      // alias: qkb free during cross-attention

  const float* nullf = nullptr;
  const float sc = 0.0625f;  // 1/sqrt(256)

  axpy_k<<<dim3(512), dim3(256), 0, stream>>>(curr, curr_pos, 0.1f, x, SCUR*DM/4);
  cvt_bf16_k<<<dim3(1024), dim3(256), 0, stream>>>(memory, memory_pos, memkb, SMEM*DM/4, 1.0f);
  cvt_bf16_k<<<dim3(1024), dim3(256), 0, stream>>>(memory, nullf, memb, SMEM*DM/4, 0.f);
  cvt_bf16_k<<<dim3(512), dim3(256), 0, stream>>>(sa_w_qkv, nullf, wb_sa_qkv, NL*3*DM*DM/4, 0.f);
  cvt_bf16_k<<<dim3(256), dim3(256), 0, stream>>>(sa_w_o,   nullf, wb_sa_o,   NL*DM*DM/4,   0.f);
  cvt_bf16_k<<<dim3(512), dim3(256), 0, stream>>>(ca_w_qkv, nullf, wb_ca_qkv, NL*3*DM*DM/4, 0.f);
  cvt_bf16_k<<<dim3(256), dim3(256), 0, stream>>>(ca_w_o,   nullf, wb_ca_o,   NL*DM*DM/4,   0.f);
  cvt_bf16_k<<<dim3(1024), dim3(256), 0, stream>>>(mlp_w1,  nullf, wb_m1,     NL*DFFN*DM/4, 0.f);
  cvt_bf16_k<<<dim3(1024), dim3(256), 0, stream>>>(mlp_w2,  nullf, wb_m2,     NL*DM*DFFN/4, 0.f);

  const dim3 blk(256);
  for (int l = 0; l < NL; l++){
    // ---- self attention ----
    ln_k<0><<<dim3(SCUR/4), blk, 0, stream>>>(x, ln1_w + l*DM, ln1_b + l*DM, (void*)t2b, SCUR);
    gemm_bt<0><<<dim3(512/64, SCUR/64), blk, 0, stream>>>(t2b, DM, wb_sa_qkv + (size_t)l*3*DM*DM, DM,
        sa_b_qkv + (size_t)l*3*DM, (void*)qkb, 512, SCUR, 512, DM);
    gemm_bt<3><<<dim3(SCUR/64, DM/64), blk, 0, stream>>>(wb_sa_qkv + ((size_t)l*3+2)*DM*DM, DM, t2b, DM,
        sa_b_qkv + (size_t)l*3*DM + 2*DM, (void*)vtsb, SCUR, DM, SCUR, DM);
    for (int c = 0; c < SCUR; c += CHs){
      int Mc = (SCUR - c) < CHs ? (SCUR - c) : CHs;
      gemm_bt<4><<<dim3(SCUR/64, Mc/64), blk, 0, stream>>>(qkb + (size_t)c*512, 512, qkb + DM, 512,
          nullf, (void*)Sbuf, SCUR, Mc, SCUR, DM);
      softmax_k<2><<<dim3(Mc), blk, 0, stream>>>(Sbuf, SCUR, sc);
      gemm_pv<<<dim3(Mc/64, 4), blk, 0, stream>>>(Sbuf, SCUR, vtsb, SCUR,
          Ppart, Mc, SCUR/4);
      reduce_pv_k<<<dim3(Mc), blk, 0, stream>>>(Ppart, Ob + (size_t)c*DM, Mc, 4);
    }
    gemm_bt<2><<<dim3(DM/64, SCUR/64), blk, 0, stream>>>(Ob, DM, wb_sa_o + (size_t)l*DM*DM, DM,
        sa_b_o + l*DM, (void*)x, DM, SCUR, DM, DM);

    // ---- cross attention ----
    ln_k<0><<<dim3(SCUR/4), blk, 0, stream>>>(x, ln2_w + l*DM, ln2_b + l*DM, (void*)t2b, SCUR);
    gemm_bt<0><<<dim3(DM/64, SCUR/64), blk, 0, stream>>>(t2b, DM, wb_ca_qkv + ((size_t)l*3+0)*DM*DM, DM,
        ca_b_qkv + l*3*DM + 0*DM, (void*)Qb, DM, SCUR, DM, DM);
    gemm_bt<0><<<dim3(DM/64, SMEM/64), blk, 0, stream>>>(memkb, DM, wb_ca_qkv + ((size_t)l*3+1)*DM*DM, DM,
        ca_b_qkv + l*3*DM + 1*DM, (void*)Kb, DM, SMEM, DM, DM);
    gemm_bt<3><<<dim3(SMEM/64, DM/64), blk, 0, stream>>>(wb_ca_qkv + ((size_t)l*3+2)*DM*DM, DM, memb, DM,
        ca_b_qkv + (size_t)l*3*DM + 2*DM, (void*)vtcb, SMEM, DM, SMEM, DM);
    for (int c = 0; c < SCUR; c += CHc){
      int Mc = (SCUR - c) < CHc ? (SCUR - c) : CHc;
      gemm_bt<4><<<dim3(SMEM/64, Mc/64), blk, 0, stream>>>(Qb + (size_t)c*DM, DM, Kb, DM,
          nullf, (void*)Sbuf, SMEM, Mc, SMEM, DM);
      softmax_k<8><<<dim3(Mc), blk, 0, stream>>>(Sbuf, SMEM, sc);
      gemm_pv<<<dim3(Mc/64, 8), blk, 0, stream>>>(Sbuf, SMEM, vtcb, SMEM,
          Ppart, Mc, SMEM/8);
      reduce_pv_k<<<dim3(Mc), blk, 0, stream>>>(Ppart, Ob + (size_t)c*DM, Mc, 8);
    }
    gemm_bt<2><<<dim3(DM/64, SCUR/64), blk, 0, stream>>>(Ob, DM, wb_ca_o + (size_t)l*DM*DM, DM,
        ca_b_o + l*DM, (void*)x, DM, SCUR, DM, DM);

    // ---- MLP ----
    ln_k<0><<<dim3(SCUR/4), blk, 0, stream>>>(x, ln3_w + l*DM, ln3_b + l*DM, (void*)t2b, SCUR);
    gemm_bt<1><<<dim3(DFFN/64, SCUR/64), blk, 0, stream>>>(t2b, DM, wb_m1 + (size_t)l*DFFN*DM, DM,
        mlp_b1 + l*DFFN, (void*)Hb, DFFN, SCUR, DFFN, DM);
    gemm_pv<<<dim3(SCUR/64, 4), blk, 0, stream>>>(Hb, DFFN, wb_m2 + (size_t)l*DM*DFFN, DFFN,
        Ppart, SCUR, DFFN/4);
    reduce_res_k<<<dim3(SCUR), blk, 0, stream>>>(Ppart, mlp_b2 + l*DM, x, SCUR, 4);
  }

  ln_k<1><<<dim3(SCUR/4), blk, 0, stream>>>(x, norm_w, norm_b, d_out, SCUR);
}